// Round 4
// baseline (547.471 us; speedup 1.0000x reference)
//
#include <hip/hip_runtime.h>
#include <math.h>
#include <stdint.h>

typedef unsigned short u16;
typedef unsigned int u32;
typedef __attribute__((ext_vector_type(4))) unsigned short u16x4;
typedef __attribute__((ext_vector_type(8))) unsigned short u16x8;
typedef __attribute__((ext_vector_type(8))) __bf16 bf16x8;
typedef __attribute__((ext_vector_type(4))) float f32x4;

#define Bn 8
#define Tn 1024
#define Cn 1024
#define Hn 16
#define Dn 64
#define Mn 8192   // B*T

#define F32_ONE_BITS 0x3F800000u

__device__ __forceinline__ float b2f(u16 u) {
  union { unsigned int i; float f; } v; v.i = ((unsigned int)u) << 16; return v.f;
}
__device__ __forceinline__ u16 f2b(float f) {
  union { float f; unsigned int i; } v; v.f = f;
  unsigned int r = v.i + 0x7fffu + ((v.i >> 16) & 1u);
  return (u16)(r >> 16);
}

__device__ __forceinline__ void async_ld16(const u16* g, u16* l) {
  __builtin_amdgcn_global_load_lds(
      (__attribute__((address_space(1))) void*)g,
      (__attribute__((address_space(3))) void*)l, 16, 0, 0);
}

template <int N> __device__ __forceinline__ void wait_vmcnt() {
  if constexpr (N == 8)      asm volatile("s_waitcnt vmcnt(8)" ::: "memory");
  else if constexpr (N == 6) asm volatile("s_waitcnt vmcnt(6)" ::: "memory");
  else if constexpr (N == 4) asm volatile("s_waitcnt vmcnt(4)" ::: "memory");
  else                       asm volatile("s_waitcnt vmcnt(0)" ::: "memory");
}
__device__ __forceinline__ void raw_barrier() {
  asm volatile("s_barrier" ::: "memory");
}

// gelu_tanh(x) == x * sigmoid(2*0.79788456*(x+0.044715x^3)); one v_exp_f32, inf-safe.
__device__ __forceinline__ float gelu_fast(float x) {
  float u2 = 1.5957691216057308f * (x + 0.044715f * x * x * x);
  return x / (1.0f + __expf(-u2));
}

// ---------------- input canonicalization: fp32 -> bf16 ----------------
__global__ __launch_bounds__(256) void cvt_x_k(const void* __restrict__ src, u16* __restrict__ dst,
                                               const u32* __restrict__ flagp) {
  bool isf32 = (*flagp == F32_ONE_BITS);
  size_t i = ((size_t)blockIdx.x * 256 + threadIdx.x) * 4;
  if (isf32) {
    f32x4 v = *reinterpret_cast<const f32x4*>((const float*)src + i);
    u16x4 o;
#pragma unroll
    for (int j = 0; j < 4; j++) o[j] = f2b(v[j]);
    *reinterpret_cast<u16x4*>(dst + i) = o;
  } else {
    *reinterpret_cast<u16x4*>(dst + i) = *reinterpret_cast<const u16x4*>((const u16*)src + i);
  }
}

struct SmallCvt { const void* src[8]; u16* dst[8]; int n[8]; };

__global__ __launch_bounds__(256) void cvt_small_k(SmallCvt p, const u32* __restrict__ flagp) {
  bool isf32 = (*flagp == F32_ONE_BITS);
  int t = blockIdx.x * 256 + threadIdx.x;
  int off = 0;
#pragma unroll
  for (int i = 0; i < 8; i++) {
    int idx = t - off;
    if (idx >= 0 && idx < p.n[i]) {
      u16 v = isf32 ? f2b(((const float*)p.src[i])[idx]) : ((const u16*)p.src[i])[idx];
      p.dst[i][idx] = v;
    }
    off += p.n[i];
  }
}

// ---------------- transpose (+convert): out[n*K+k] = bf16(in[k*N+n]), in is [K][N] ----------------
__global__ __launch_bounds__(256) void transpose_k(const void* __restrict__ in,
                                                   u16* __restrict__ out, int K, int N,
                                                   const u32* __restrict__ flagp) {
  bool isf32 = (*flagp == F32_ONE_BITS);
  __shared__ u16 tile[32][33];
  int c0 = blockIdx.x * 32, r0 = blockIdx.y * 32;
  int tx = threadIdx.x, ty = threadIdx.y;  // block (32,8)
#pragma unroll
  for (int i = 0; i < 4; i++) {
    size_t idx = (size_t)(r0 + ty + i * 8) * N + c0 + tx;
    tile[ty + i * 8][tx] = isf32 ? f2b(((const float*)in)[idx]) : ((const u16*)in)[idx];
  }
  __syncthreads();
#pragma unroll
  for (int i = 0; i < 4; i++)
    out[(size_t)(c0 + ty + i * 8) * K + r0 + tx] = tile[tx][ty + i * 8];
}

// ---------------- LayerNorm over C=1024; one block (256 thr) per row ----------------
__global__ __launch_bounds__(256) void ln_k(const u16* __restrict__ x, const u16* __restrict__ w,
                                            const u16* __restrict__ bi, u16* __restrict__ out) {
  int row = blockIdx.x, tid = threadIdx.x;
  const u16* xr = x + (size_t)row * Cn;
  u16x4 xv = *reinterpret_cast<const u16x4*>(xr + tid * 4);
  float v0 = b2f(xv[0]), v1 = b2f(xv[1]), v2 = b2f(xv[2]), v3 = b2f(xv[3]);
  float s = v0 + v1 + v2 + v3;
  float s2 = v0 * v0 + v1 * v1 + v2 * v2 + v3 * v3;
#pragma unroll
  for (int m = 1; m < 64; m <<= 1) {
    s += __shfl_xor(s, m, 64);
    s2 += __shfl_xor(s2, m, 64);
  }
  __shared__ float rs_[4], rs2_[4];
  int wave = tid >> 6, lane = tid & 63;
  if (lane == 0) { rs_[wave] = s; rs2_[wave] = s2; }
  __syncthreads();
  s = rs_[0] + rs_[1] + rs_[2] + rs_[3];
  s2 = rs2_[0] + rs2_[1] + rs2_[2] + rs2_[3];
  float mu = s * (1.0f / Cn);
  float var = s2 * (1.0f / Cn) - mu * mu;
  float rstd = rsqrtf(var + 1e-5f);
  u16x4 wv = *reinterpret_cast<const u16x4*>(w + tid * 4);
  u16x4 bv = *reinterpret_cast<const u16x4*>(bi + tid * 4);
  u16x4 ov;
  float vv[4] = {v0, v1, v2, v3};
#pragma unroll
  for (int j = 0; j < 4; j++)
    ov[j] = f2b((vv[j] - mu) * rstd * b2f(wv[j]) + b2f(bv[j]));
  *reinterpret_cast<u16x4*>(out + (size_t)row * Cn + tid * 4) = ov;
}

// ---------------- MFMA GEMM, 256xBN tile, 8 waves, BK=64, 4-phase-per-K-tile pipeline ----
// Phases (h,kc), h = mi-half. Per phase: {ds_read frag subtile, 1-3 global_load_lds issues,
// s_barrier, setprio(1), 16 (or 8) MFMA, setprio(0), s_barrier}. Row-band freeing:
// A bands {0-63,128-191} + all B die after phase1 (B kept in regs for both kc) -> tile t+2's
// A0/A2/B* issue in phases 2/3; A bands {64-127,192-255} die after phase3 -> tile t+1's
// A1/A3 issue in NEXT tile's phases 0/1 (other LDS buffer). One counted vmcnt per K-tile
// (phase 3): steady 2+NB outstanding = tile t+2's in-tile issues; never 0 mid-loop.
// XOR swizzle (slot j^(row&7) within each row's 8 chunks) on both stage-src and frag reads.
template <int BN_T, int GELU, int RES, int F32OUT>
__global__ __launch_bounds__(512, 2) void gemm3_k(const u16* __restrict__ A, const u16* __restrict__ BT,
                                                  const u16* __restrict__ bias, const u16* __restrict__ res,
                                                  void* __restrict__ Cout, int M, int N, int K) {
  constexpr int NI = BN_T / 64;   // 4 (BN=256) or 2 (BN=128)
  constexpr int NB = NI;          // B staging issues per thread
  constexpr int AE = 256 * 64;    // u16 elems per A buffer
  constexpr int BE = BN_T * 64;

  __shared__ __align__(16) u16 As[2 * AE];
  __shared__ __align__(16) u16 Bs[2 * BE];

  int tid = threadIdx.x, wave = tid >> 6, lane = tid & 63;
  int l15 = lane & 15, quad = lane >> 4;

  // XCD-aware bijective swizzle (all grids are %8==0)
  int nbx = gridDim.x;
  int nwg = nbx * gridDim.y;
  int lin = blockIdx.y * nbx + blockIdx.x;
  int cpx = nwg >> 3;
  int swz = (lin & 7) * cpx + (lin >> 3);
  int m0 = (swz / nbx) * 256;
  int n0 = (swz % nbx) * BN_T;

  int wm = (wave >> 2) * 128;         // 2 M-groups
  int wn = (wave & 3) * (NI * 16);    // 4 N-groups

  int offA0, offA1, offB0, offB1;
  {
    int x0 = ((0 + quad) ^ (l15 & 7)) * 8;
    int x1 = ((4 + quad) ^ (l15 & 7)) * 8;
    offA0 = (wm + l15) * 64 + x0;
    offA1 = (wm + l15) * 64 + x1;
    offB0 = (wn + l15) * 64 + x0;
    offB1 = (wn + l15) * 64 + x1;
  }

  // staging: A issue i covers rows [64i,64i+64); same for B. chunk c = i*512+tid.
  const u16* aS[4]; int aD[4];
#pragma unroll
  for (int i = 0; i < 4; i++) {
    int c = i * 512 + tid;
    int row = c >> 3, j = (c & 7) ^ (row & 7);
    aS[i] = A + (size_t)(m0 + row) * K + j * 8;
    aD[i] = c * 8;
  }
  const u16* bS[NB]; int bD[NB];
#pragma unroll
  for (int i = 0; i < NB; i++) {
    int c = i * 512 + tid;
    int row = c >> 3, j = (c & 7) ^ (row & 7);
    bS[i] = BT + (size_t)(n0 + row) * K + j * 8;
    bD[i] = c * 8;
  }

#define ISSA(T, I) async_ld16(aS[I] + (size_t)(T) * 64, &As[((T) & 1) * AE + aD[I]])
#define ISSB(T, I) async_ld16(bS[I] + (size_t)(T) * 64, &Bs[((T) & 1) * BE + bD[I]])
#define LDF(P) (*reinterpret_cast<const bf16x8*>(P))
#define MM(AV, BV, CC) CC = __builtin_amdgcn_mfma_f32_16x16x32_bf16(AV, BV, CC, 0, 0, 0)

  f32x4 acc[8][NI];
#pragma unroll
  for (int mi = 0; mi < 8; mi++)
#pragma unroll
    for (int ni = 0; ni < NI; ni++) acc[mi][ni] = (f32x4){0.f, 0.f, 0.f, 0.f};

  int NT = K >> 6;

  // prologue: tiles 0 and 1 fully issued; wait tile 0 only
#pragma unroll
  for (int i = 0; i < 4; i++) ISSA(0, i);
#pragma unroll
  for (int i = 0; i < NB; i++) ISSB(0, i);
#pragma unroll
  for (int i = 0; i < 4; i++) ISSA(1, i);
#pragma unroll
  for (int i = 0; i < NB; i++) ISSB(1, i);
  wait_vmcnt<4 + NB>();
  raw_barrier();

  bf16x8 bv[NI][2];

#pragma unroll 2
  for (int t = 0; t < NT; ++t) {
    const u16* Ab = &As[(t & 1) * AE];
    const u16* Bb = &Bs[(t & 1) * BE];
    bool haveN = (t >= 1) && (t + 1 < NT);
    bool haveNN = (t + 2 < NT);

    // ---- phase 0: mi 0-3, kc0; read B kc0 ----
    {
      bf16x8 a0 = LDF(Ab + offA0);
      bf16x8 a1 = LDF(Ab + offA0 + 1024);
      bf16x8 a2 = LDF(Ab + offA0 + 2048);
      bf16x8 a3 = LDF(Ab + offA0 + 3072);
#pragma unroll
      for (int ni = 0; ni < NI; ni++) bv[ni][0] = LDF(Bb + offB0 + ni * 1024);
      if (haveN) ISSA(t + 1, 1);
      raw_barrier();
      __builtin_amdgcn_s_setprio(1);
#pragma unroll
      for (int ni = 0; ni < NI; ni++) {
        MM(a0, bv[ni][0], acc[0][ni]);
        MM(a1, bv[ni][0], acc[1][ni]);
        MM(a2, bv[ni][0], acc[2][ni]);
        MM(a3, bv[ni][0], acc[3][ni]);
      }
      __builtin_amdgcn_s_setprio(0);
      raw_barrier();
    }
    // ---- phase 1: mi 0-3, kc1; read B kc1 ----
    {
      bf16x8 a0 = LDF(Ab + offA1);
      bf16x8 a1 = LDF(Ab + offA1 + 1024);
      bf16x8 a2 = LDF(Ab + offA1 + 2048);
      bf16x8 a3 = LDF(Ab + offA1 + 3072);
#pragma unroll
      for (int ni = 0; ni < NI; ni++) bv[ni][1] = LDF(Bb + offB1 + ni * 1024);
      if (haveN) ISSA(t + 1, 3);
      raw_barrier();
      __builtin_amdgcn_s_setprio(1);
#pragma unroll
      for (int ni = 0; ni < NI; ni++) {
        MM(a0, bv[ni][1], acc[0][ni]);
        MM(a1, bv[ni][1], acc[1][ni]);
        MM(a2, bv[ni][1], acc[2][ni]);
        MM(a3, bv[ni][1], acc[3][ni]);
      }
      __builtin_amdgcn_s_setprio(0);
      raw_barrier();
    }
    // ---- phase 2: mi 4-7, kc0 (A rows 0-63/128-191 + all B freed after phase 1) ----
    {
      bf16x8 a0 = LDF(Ab + offA0 + 4096);
      bf16x8 a1 = LDF(Ab + offA0 + 5120);
      bf16x8 a2 = LDF(Ab + offA0 + 6144);
      bf16x8 a3 = LDF(Ab + offA0 + 7168);
      if (haveNN) {
        ISSA(t + 2, 0);
        ISSB(t + 2, 0);
        if constexpr (NB == 4) ISSB(t + 2, 1);
      }
      raw_barrier();
      __builtin_amdgcn_s_setprio(1);
#pragma unroll
      for (int ni = 0; ni < NI; ni++) {
        MM(a0, bv[ni][0], acc[4][ni]);
        MM(a1, bv[ni][0], acc[5][ni]);
        MM(a2, bv[ni][0], acc[6][ni]);
        MM(a3, bv[ni][0], acc[7][ni]);
      }
      __builtin_amdgcn_s_setprio(0);
      raw_barrier();
    }
    // ---- phase 3: mi 4-7, kc1 + counted vmcnt (once per K-tile) ----
    {
      bf16x8 a0 = LDF(Ab + offA1 + 4096);
      bf16x8 a1 = LDF(Ab + offA1 + 5120);
      bf16x8 a2 = LDF(Ab + offA1 + 6144);
      bf16x8 a3 = LDF(Ab + offA1 + 7168);
      if (haveNN) {
        ISSA(t + 2, 2);
        if constexpr (NB == 4) { ISSB(t + 2, 2); ISSB(t + 2, 3); }
        else ISSB(t + 2, 1);
      }
      raw_barrier();
      __builtin_amdgcn_s_setprio(1);
#pragma unroll
      for (int ni = 0; ni < NI; ni++) {
        MM(a0, bv[ni][1], acc[4][ni]);
        MM(a1, bv[ni][1], acc[5][ni]);
        MM(a2, bv[ni][1], acc[6][ni]);
        MM(a3, bv[ni][1], acc[7][ni]);
      }
      __builtin_amdgcn_s_setprio(0);
      if (haveNN) wait_vmcnt<2 + NB>();  // tile t+1 fully landed; t+2's stay in flight
      else wait_vmcnt<0>();
      raw_barrier();
    }
  }
#undef ISSA
#undef ISSB
#undef LDF
#undef MM

  // epilogue
#pragma unroll
  for (int ni = 0; ni < NI; ni++) {
    int col = n0 + wn + ni * 16 + l15;
    float bval = b2f(bias[col]);
#pragma unroll
    for (int mi = 0; mi < 8; mi++) {
#pragma unroll
      for (int r = 0; r < 4; r++) {
        int row = m0 + wm + mi * 16 + quad * 4 + r;
        float v = acc[mi][ni][r] + bval;
        if (GELU) v = gelu_fast(v);
        if (RES) v += b2f(res[(size_t)row * N + col]);
        if (F32OUT)
          ((float*)Cout)[(size_t)row * N + col] = v;
        else
          ((u16*)Cout)[(size_t)row * N + col] = f2b(v);
      }
    }
  }
}

// ---------------- MFMA flash attention, paired q-tiles (lo, 15-lo) ----------------
// grid (bh=128, lo=8): uniform 17 score-tiles/block; shared-prefix K/V staged once for
// both q-tiles; K double-buffered via swizzled global_load_lds; V^T reg-staged with
// async-split. Tile processing is a MACRO (no address-taken arrays -> no scratch demotion).
#define ATTN_PROC(QF, O, M_R, L_R, Q0, KV0, KSB)                                      \
  do {                                                                                \
    float sv[4][4];                                                                   \
    _Pragma("unroll")                                                                 \
    for (int ni = 0; ni < 4; ni++) {                                                  \
      f32x4 z = (f32x4){0.f, 0.f, 0.f, 0.f};                                          \
      _Pragma("unroll")                                                               \
      for (int kc = 0; kc < 2; kc++) {                                                \
        bf16x8 bfr = *reinterpret_cast<const bf16x8*>((KSB) + offKb[kc] + ni * 1024); \
        z = __builtin_amdgcn_mfma_f32_16x16x32_bf16(QF[kc], bfr, z, 0, 0, 0);         \
      }                                                                               \
      _Pragma("unroll")                                                               \
      for (int r = 0; r < 4; r++) sv[ni][r] = z[r];                                   \
    }                                                                                 \
    bool diag = ((KV0) + 64 > (Q0));                                                  \
    _Pragma("unroll")                                                                 \
    for (int ni = 0; ni < 4; ni++)                                                    \
      _Pragma("unroll")                                                               \
      for (int r = 0; r < 4; r++) {                                                   \
        float v = sv[ni][r] * 0.125f;                                                 \
        if (diag && ((KV0) + ni * 16 + l15 > (Q0) + quad * 4 + r)) v = -1e30f;        \
        sv[ni][r] = v;                                                                \
      }                                                                               \
    float mt[4], al[4], rs[4];                                                        \
    _Pragma("unroll")                                                                 \
    for (int r = 0; r < 4; r++) {                                                     \
      mt[r] = fmaxf(fmaxf(sv[0][r], sv[1][r]), fmaxf(sv[2][r], sv[3][r]));            \
      _Pragma("unroll")                                                               \
      for (int m = 1; m <= 8; m <<= 1) mt[r] = fmaxf(mt[r], __shfl_xor(mt[r], m, 64));\
      float mn = fmaxf(M_R[r], mt[r]);                                                \
      al[r] = __expf(M_R[r] - mn);                                                    \
      M_R[r] = mn;                                                                    \
      rs[r] = 0.f;                                                                    \
    }                                                                                 \
    _Pragma("unroll")                                                                 \
    for (int ni = 0; ni < 4; ni++)                                                    \
      _Pragma("unroll")                                                               \
      for (int r = 0; r < 4; r++) {                                                   \
        float p = __expf(sv[ni][r] - M_R[r]);                                         \
        sv[ni][r] = p;                                                                \
        rs[r] += p;                                                                   \
      }                                                                               \
    _Pragma("unroll")                                                                 \
    for (int r = 0; r < 4; r++) {                                                     \
      _Pragma("unroll")                                                               \
      for (int m = 1; m <= 8; m <<= 1) rs[r] += __shfl_xor(rs[r], m, 64);             \
      L_R[r] = L_R[r] * al[r] + rs[r];                                                \
    }                                                                                 \
    _Pragma("unroll")                                                                 \
    for (int dn = 0; dn < 4; dn++)                                                    \
      _Pragma("unroll")                                                               \
      for (int r = 0; r < 4; r++) O[dn][r] *= al[r];                                  \
    _Pragma("unroll")                                                                 \
    for (int ni = 0; ni < 4; ni++)                                                    \
      _Pragma("unroll")                                                               \
      for (int r = 0; r < 4; r++)                                                     \
        Ps[wave][pwBase + r * 72 + ni * 16] = f2b(sv[ni][r]);                         \
    _Pragma("unroll")                                                                 \
    for (int kc = 0; kc < 2; kc++) {                                                  \
      bf16x8 afr = *reinterpret_cast<const bf16x8*>(&Ps[wave][prBase + kc * 32]);     \
      _Pragma("unroll")                                                               \
      for (int dn = 0; dn < 4; dn++) {                                                \
        bf16x8 bfr = *reinterpret_cast<const bf16x8*>(&VTs[vrBase + dn * 1152 + kc * 32]); \
        O[dn] = __builtin_amdgcn_mfma_f32_16x16x32_bf16(afr, bfr, O[dn], 0, 0, 0);    \
      }                                                                               \
    }                                                                                 \
  } while (0)

__global__ __launch_bounds__(256, 4) void attn_k(const u16* __restrict__ qkv, u16* __restrict__ y) {
  int bh = blockIdx.x;
  int lo = blockIdx.y;        // 0..7
  int hi = 15 - lo;           // 15..8
  int b = bh >> 4, h = bh & 15;
  int tid = threadIdx.x, wave = tid >> 6, lane = tid & 63;
  int l15 = lane & 15, quad = lane >> 4;

  __shared__ __align__(16) u16 Ks[2][64 * 64];  // XOR-swizzled [key][chunk], dbuf
  __shared__ __align__(16) u16 VTs[64 * 72];    // [d][key], stride 72
  __shared__ __align__(16) u16 Ps[4][16 * 72];  // per-wave P [q][key], stride 72

  const u16* base = qkv + (size_t)b * Tn * 3072 + h * 64;
  int q0_lo = lo * 64 + wave * 16;
  int q0_hi = hi * 64 + wave * 16;

  bf16x8 qf_lo[2], qf_hi[2];
#pragma unroll
  for (int kc = 0; kc < 2; kc++) {
    qf_lo[kc] = *reinterpret_cast<const bf16x8*>(base + (size_t)(q0_lo + l15) * 3072 + kc * 32 + quad * 8);
    qf_hi[kc] = *reinterpret_cast<const bf16x8*>(base + (size_t)(q0_hi + l15) * 3072 + kc * 32 + quad * 8);
  }

  // K fragment read offsets: row R = ni*16+l15 -> R&7 == l15&7, so XOR term is ni-free.
  int offKb[2];
#pragma unroll
  for (int kc = 0; kc < 2; kc++)
    offKb[kc] = l15 * 64 + (((kc * 4 + quad) ^ (l15 & 7)) * 8);

  // K staging: 512 chunks of 16B; thread issue i covers chunk c = wave*128 + i*64 + lane
  int kSrcOff[2], kDstOff[2];
#pragma unroll
  for (int i = 0; i < 2; i++) {
    int c = wave * 128 + i * 64 + lane;
    int row = c >> 3, j = (c & 7) ^ (row & 7);
    kSrcOff[i] = row * 3072 + j * 8;
    kDstOff[i] = c * 8;
  }
  const u16* kBase = base + 1024;
  const u16* vBase = base + 2048;
  int kp = tid & 31, dgroup = tid >> 5;
  u32* vtw = reinterpret_cast<u32*>(VTs);

  // prologue: issue tile 0 (K direct-to-LDS, V to regs)
#pragma unroll
  for (int i = 0; i < 2; i++) async_ld16(kBase + kSrcOff[i], &Ks[0][kDstOff[i]]);
  u16x8 va, vb;
  {
    const u16* vS = vBase + (size_t)(2 * kp) * 3072 + dgroup * 8;
    va = *reinterpret_cast<const u16x8*>(vS);
    vb = *reinterpret_cast<const u16x8*>(vS + 3072);
  }

  f32x4 o_lo[4], o_hi[4];
  float m_lo[4], l_lo[4], m_hi[4], l_hi[4];
#pragma unroll
  for (int i = 0; i < 4; i++) {
    o_lo[i] = (f32x4){0.f, 0.f, 0.f, 0.f};
    o_hi[i] = (f32x4){0.f, 0.f, 0.f, 0.f};
    m_lo[i] = -1e30f; m_hi[i] = -1e30f;
    l_lo[i] = 0.f;    l_hi[i] = 0.f;
  }

  int pwBase = quad * 4 * 72 + l15;           // + r*72 + ni*16
  int prBase = l15 * 72 + quad * 8;           // + kc*32
  int vrBase = l15 * 72 + quad * 8;           // + dn*1152 + kc*32

  int kvend_hi = hi * 64, kvend_lo = lo * 64;
  int buf = 0;
  for (int kv0 = 0; kv0 <= kvend_hi; kv0 += 64) {
    __syncthreads();  // A: prev-iter LDS reads done; drains K(t)->LDS + V(t)->regs
    // V(t) regs -> LDS (u32-packed key-pairs, all 32 banks)
#pragma unroll
    for (int i = 0; i < 8; i++)
      vtw[(dgroup * 8 + i) * 36 + kp] = (u32)va[i] | ((u32)vb[i] << 16);
    __syncthreads();  // B: staging visible
    if (kv0 + 64 <= kvend_hi) {  // issue tile t+1 (stays in flight across compute)
      const u16* kS = kBase + (size_t)(kv0 + 64) * 3072;
#pragma unroll
      for (int i = 0; i < 2; i++) async_ld16(kS + kSrcOff[i], &Ks[buf ^ 1][kDstOff[i]]);
      const u16* vS = vBase + (size_t)(kv0 + 64 + 2 * kp) * 3072 + dgroup * 8;
      va = *reinterpret_cast<const u16x8*>(vS);
      vb = *reinterpret_cast<const u16x8*>(vS + 3072);
    }
    {
      const u16* KsB = &Ks[buf][0];
      ATTN_PROC(qf_hi, o_hi, m_hi, l_hi, q0_hi, kv0, KsB);
      if (kv0 <= kvend_lo)
        ATTN_PROC(qf_lo, o_lo, m_lo, l_lo, q0_lo, kv0, KsB);
    }
    buf ^= 1;
  }

#pragma unroll
  for (int r = 0; r < 4; r++) {
    float inv = 1.0f / l_hi[r];
    int row = b * Tn + q0_hi + quad * 4 + r;
#pragma unroll
    for (int dn = 0; dn < 4; dn++)
      y[(size_t)row * Cn + h * 64 + dn * 16 + l15] = f2b(o_hi[dn][r] * inv);
  }
#pragma unroll
  for (int r = 0; r < 4; r++) {
    float inv = 1.0f / l_lo[r];
    int row = b * Tn + q0_lo + quad * 4 + r;
#pragma unroll
    for (int dn = 0; dn < 4; dn++)
      y[(size_t)row * Cn + h * 64 + dn * 16 + l15] = f2b(o_lo[dn][r] * inv);
  }
}

// ---------------- launcher ----------------
extern "C" void kernel_launch(void* const* d_in, const int* in_sizes, int n_in,
                              void* d_out, int out_size, void* d_ws, size_t ws_size,
                              hipStream_t stream) {
  const void* x      = d_in[0];
  const void* ln1_w  = d_in[1];
  const void* ln1_b  = d_in[2];
  const void* w_qkv  = d_in[3];
  const void* b_qkv  = d_in[4];
  const void* w_o    = d_in[5];
  const void* b_o    = d_in[6];
  const void* ln2_w  = d_in[7];
  const void* ln2_b  = d_in[8];
  const void* w_fc   = d_in[9];
  const void* b_fc   = d_in[10];
  const void* w_proj = d_in[11];
  const void* b_proj = d_in[12];
  const u32* flagp = (const u32*)ln1_w;

  size_t off = 0;
  char* wsb = (char*)d_ws;
  auto alloc = [&](size_t bytes) {
    void* p = wsb + off;
    off += (bytes + 255) & ~(size_t)255;
    return (u16*)p;
  };
  u16* wqkvT  = alloc((size_t)3072 * 1024 * 2);
  u16* woT    = alloc((size_t)1024 * 1024 * 2);
  u16* wfcT   = alloc((size_t)4096 * 1024 * 2);
  u16* wprojT = alloc((size_t)1024 * 4096 * 2);
  u16* xb     = alloc((size_t)Mn * 1024 * 2);
  u16* sm     = alloc((size_t)16384 * 2);
  u16* xn     = alloc((size_t)Mn * 1024 * 2);
  u16* ybuf   = alloc((size_t)Mn * 1024 * 2);
  u16* x1     = alloc((size_t)Mn * 1024 * 2);
  u16* big    = alloc((size_t)Mn * 4096 * 2);
  u16* qkvbuf = big;
  u16* hbuf   = big;
  if (off > ws_size) return;

  u16* LW1 = sm;          // 1024
  u16* LB1 = sm + 1024;   // 1024
  u16* BQKV = sm + 2048;  // 3072
  u16* BO  = sm + 5120;   // 1024
  u16* LW2 = sm + 6144;   // 1024
  u16* LB2 = sm + 7168;   // 1024
  u16* BFC = sm + 8192;   // 4096
  u16* BPJ = sm + 12288;  // 1024

  SmallCvt sc;
  sc.src[0] = ln1_w;  sc.dst[0] = LW1;  sc.n[0] = 1024;
  sc.src[1] = ln1_b;  sc.dst[1] = LB1;  sc.n[1] = 1024;
  sc.src[2] = b_qkv;  sc.dst[2] = BQKV; sc.n[2] = 3072;
  sc.src[3] = b_o;    sc.dst[3] = BO;   sc.n[3] = 1024;
  sc.src[4] = ln2_w;  sc.dst[4] = LW2;  sc.n[4] = 1024;
  sc.src[5] = ln2_b;  sc.dst[5] = LB2;  sc.n[5] = 1024;
  sc.src[6] = b_fc;   sc.dst[6] = BFC;  sc.n[6] = 4096;
  sc.src[7] = b_proj; sc.dst[7] = BPJ;  sc.n[7] = 1024;

  hipLaunchKernelGGL(cvt_small_k, dim3(52), dim3(256), 0, stream, sc, flagp);
  hipLaunchKernelGGL(cvt_x_k, dim3(Mn * 1024 / 4 / 256), dim3(256), 0, stream, x, xb, flagp);

  dim3 tb(32, 8);
  hipLaunchKernelGGL(transpose_k, dim3(3072 / 32, 1024 / 32), tb, 0, stream, w_qkv, wqkvT, 1024, 3072, flagp);
  hipLaunchKernelGGL(transpose_k, dim3(1024 / 32, 1024 / 32), tb, 0, stream, w_o, woT, 1024, 1024, flagp);
  hipLaunchKernelGGL(transpose_k, dim3(4096 / 32, 1024 / 32), tb, 0, stream, w_fc, wfcT, 1024, 4096, flagp);
  hipLaunchKernelGGL(transpose_k, dim3(1024 / 32, 4096 / 32), tb, 0, stream, w_proj, wprojT, 4096, 1024, flagp);

  hipLaunchKernelGGL(ln_k, dim3(Mn), dim3(256), 0, stream, xb, LW1, LB1, xn);
  hipLaunchKernelGGL((gemm3_k<256, 0, 0, 0>), dim3(3072 / 256, Mn / 256), dim3(512), 0, stream,
                     xn, wqkvT, BQKV, (const u16*)nullptr, (void*)qkvbuf, Mn, 3072, 1024);
  hipLaunchKernelGGL(attn_k, dim3(Bn * Hn, 8), dim3(256), 0, stream, qkvbuf, ybuf);
  hipLaunchKernelGGL((gemm3_k<128, 0, 1, 0>), dim3(1024 / 128, Mn / 256), dim3(512), 0, stream,
                     ybuf, woT, BO, xb, (void*)x1, Mn, 1024, 1024);
  hipLaunchKernelGGL(ln_k, dim3(Mn), dim3(256), 0, stream, x1, LW2, LB2, xn);
  hipLaunchKernelGGL((gemm3_k<256, 1, 0, 0>), dim3(4096 / 256, Mn / 256), dim3(512), 0, stream,
                     xn, wfcT, BFC, (const u16*)nullptr, (void*)hbuf, Mn, 4096, 1024);
  hipLaunchKernelGGL((gemm3_k<128, 0, 1, 1>), dim3(1024 / 128, Mn / 256), dim3(512), 0, stream,
                     hbuf, wprojT, BPJ, x1, d_out, Mn, 1024, 4096);
}

// Round 6
// 531.541 us; speedup vs baseline: 1.0300x; 1.0300x over previous
//
#include <hip/hip_runtime.h>
#include <math.h>
#include <stdint.h>

typedef unsigned short u16;
typedef unsigned int u32;
typedef __attribute__((ext_vector_type(4))) unsigned short u16x4;
typedef __attribute__((ext_vector_type(8))) unsigned short u16x8;
typedef __attribute__((ext_vector_type(8))) __bf16 bf16x8;
typedef __attribute__((ext_vector_type(4))) float f32x4;

#define Bn 8
#define Tn 1024
#define Cn 1024
#define Hn 16
#define Dn 64
#define Mn 8192   // B*T

#define F32_ONE_BITS 0x3F800000u

__device__ __forceinline__ float b2f(u16 u) {
  union { unsigned int i; float f; } v; v.i = ((unsigned int)u) << 16; return v.f;
}
__device__ __forceinline__ u16 f2b(float f) {
  union { float f; unsigned int i; } v; v.f = f;
  unsigned int r = v.i + 0x7fffu + ((v.i >> 16) & 1u);
  return (u16)(r >> 16);
}

__device__ __forceinline__ void async_ld16(const u16* g, u16* l) {
  __builtin_amdgcn_global_load_lds(
      (__attribute__((address_space(1))) void*)g,
      (__attribute__((address_space(3))) void*)l, 16, 0, 0);
}

template <int N> __device__ __forceinline__ void wait_vmcnt() {
  if constexpr (N == 8)      asm volatile("s_waitcnt vmcnt(8)" ::: "memory");
  else if constexpr (N == 6) asm volatile("s_waitcnt vmcnt(6)" ::: "memory");
  else if constexpr (N == 4) asm volatile("s_waitcnt vmcnt(4)" ::: "memory");
  else                       asm volatile("s_waitcnt vmcnt(0)" ::: "memory");
}
__device__ __forceinline__ void raw_barrier() {
  asm volatile("s_barrier" ::: "memory");
}

// gelu_tanh(x) == x * sigmoid(2*0.79788456*(x+0.044715x^3)); one v_exp_f32, inf-safe.
__device__ __forceinline__ float gelu_fast(float x) {
  float u2 = 1.5957691216057308f * (x + 0.044715f * x * x * x);
  return x / (1.0f + __expf(-u2));
}

// ---------------- input canonicalization: fp32 -> bf16 ----------------
__global__ __launch_bounds__(256) void cvt_x_k(const void* __restrict__ src, u16* __restrict__ dst,
                                               const u32* __restrict__ flagp) {
  bool isf32 = (*flagp == F32_ONE_BITS);
  size_t i = ((size_t)blockIdx.x * 256 + threadIdx.x) * 4;
  if (isf32) {
    f32x4 v = *reinterpret_cast<const f32x4*>((const float*)src + i);
    u16x4 o;
#pragma unroll
    for (int j = 0; j < 4; j++) o[j] = f2b(v[j]);
    *reinterpret_cast<u16x4*>(dst + i) = o;
  } else {
    *reinterpret_cast<u16x4*>(dst + i) = *reinterpret_cast<const u16x4*>((const u16*)src + i);
  }
}

struct SmallCvt { const void* src[8]; u16* dst[8]; int n[8]; };

__global__ __launch_bounds__(256) void cvt_small_k(SmallCvt p, const u32* __restrict__ flagp) {
  bool isf32 = (*flagp == F32_ONE_BITS);
  int t = blockIdx.x * 256 + threadIdx.x;
  int off = 0;
#pragma unroll
  for (int i = 0; i < 8; i++) {
    int idx = t - off;
    if (idx >= 0 && idx < p.n[i]) {
      u16 v = isf32 ? f2b(((const float*)p.src[i])[idx]) : ((const u16*)p.src[i])[idx];
      p.dst[i][idx] = v;
    }
    off += p.n[i];
  }
}

// ---------------- transpose (+convert): out[n*K+k] = bf16(in[k*N+n]), in is [K][N] ----------------
__global__ __launch_bounds__(256) void transpose_k(const void* __restrict__ in,
                                                   u16* __restrict__ out, int K, int N,
                                                   const u32* __restrict__ flagp) {
  bool isf32 = (*flagp == F32_ONE_BITS);
  __shared__ u16 tile[32][33];
  int c0 = blockIdx.x * 32, r0 = blockIdx.y * 32;
  int tx = threadIdx.x, ty = threadIdx.y;  // block (32,8)
#pragma unroll
  for (int i = 0; i < 4; i++) {
    size_t idx = (size_t)(r0 + ty + i * 8) * N + c0 + tx;
    tile[ty + i * 8][tx] = isf32 ? f2b(((const float*)in)[idx]) : ((const u16*)in)[idx];
  }
  __syncthreads();
#pragma unroll
  for (int i = 0; i < 4; i++)
    out[(size_t)(c0 + ty + i * 8) * K + r0 + tx] = tile[tx][ty + i * 8];
}

// ---------------- LayerNorm over C=1024; one block (256 thr) per row ----------------
__global__ __launch_bounds__(256) void ln_k(const u16* __restrict__ x, const u16* __restrict__ w,
                                            const u16* __restrict__ bi, u16* __restrict__ out) {
  int row = blockIdx.x, tid = threadIdx.x;
  const u16* xr = x + (size_t)row * Cn;
  u16x4 xv = *reinterpret_cast<const u16x4*>(xr + tid * 4);
  float v0 = b2f(xv[0]), v1 = b2f(xv[1]), v2 = b2f(xv[2]), v3 = b2f(xv[3]);
  float s = v0 + v1 + v2 + v3;
  float s2 = v0 * v0 + v1 * v1 + v2 * v2 + v3 * v3;
#pragma unroll
  for (int m = 1; m < 64; m <<= 1) {
    s += __shfl_xor(s, m, 64);
    s2 += __shfl_xor(s2, m, 64);
  }
  __shared__ float rs_[4], rs2_[4];
  int wave = tid >> 6, lane = tid & 63;
  if (lane == 0) { rs_[wave] = s; rs2_[wave] = s2; }
  __syncthreads();
  s = rs_[0] + rs_[1] + rs_[2] + rs_[3];
  s2 = rs2_[0] + rs2_[1] + rs2_[2] + rs2_[3];
  float mu = s * (1.0f / Cn);
  float var = s2 * (1.0f / Cn) - mu * mu;
  float rstd = rsqrtf(var + 1e-5f);
  u16x4 wv = *reinterpret_cast<const u16x4*>(w + tid * 4);
  u16x4 bv = *reinterpret_cast<const u16x4*>(bi + tid * 4);
  u16x4 ov;
  float vv[4] = {v0, v1, v2, v3};
#pragma unroll
  for (int j = 0; j < 4; j++)
    ov[j] = f2b((vv[j] - mu) * rstd * b2f(wv[j]) + b2f(bv[j]));
  *reinterpret_cast<u16x4*>(out + (size_t)row * Cn + tid * 4) = ov;
}

// ---------------- gemm5: 256x256 quadrant-phase pipeline (m201-style) --------------------
// BM=BN=256, BK=64, 8 waves (512 thr). Per K-tile 4 phases = C-quadrants in order
// (0,0),(0,1),(1,1),(1,0); each phase touches exactly ONE A-half (128 rows) and ONE B-half,
// reusing the shared operand's register frags between adjacent phases (reads/phase 12,4,8,4).
// LDS: per matrix 4 half-slots of 128x64 u16 (A0:{0,1} A1:{2,3} by tile parity) = 128 KiB.
// Staging during tile t (2 gloads/thread/phase): p0:A0(t+1) p1:B0(t+1) p2:B1(t+1) p3:A1(t+1)
// -> first-use lags 4,3,3,3 phases. s_waitcnt vmcnt(4) at every phase end keeps exactly
// 2 half-tiles outstanding; consumed halves are always retired 1+ barrier before their reads.
// XOR swizzle: k-chunk j of row r at slot j^(r&7); applied on stage src and frag reads.
template <int GELU, int RES, int F32OUT>
__global__ __launch_bounds__(512, 2) void gemm5_k(const u16* __restrict__ A, const u16* __restrict__ BT,
                                                  const u16* __restrict__ bias, const u16* __restrict__ res,
                                                  void* __restrict__ Cout, int M, int N, int K) {
  __shared__ __align__(16) u16 As[4 * 128 * 64];
  __shared__ __align__(16) u16 Bs[4 * 128 * 64];

  int tid = threadIdx.x, wave = tid >> 6, lane = tid & 63;
  int l15 = lane & 15, quad = lane >> 4;

  // XCD-aware bijective swizzle (all grids %8==0)
  int nbx = gridDim.x;
  int nwg = nbx * gridDim.y;
  int lin = blockIdx.y * nbx + blockIdx.x;
  int cpx = nwg >> 3;
  int swz = (lin & 7) * cpx + (lin >> 3);
  int m0 = (swz / nbx) * 256;
  int n0 = (swz % nbx) * 256;

  int wqm = (wave >> 2) * 64;   // within-quadrant row offset (0/64)
  int wqn = (wave & 3) * 32;    // within-quadrant col offset (0..96)

  // frag read offsets within a 128x64 half-slot (wqm,wqn,mi*16,ni*16 are 0 mod 8)
  int offA[2], offB[2];
#pragma unroll
  for (int kc = 0; kc < 2; kc++) {
    int x = ((kc * 4 + quad) ^ (l15 & 7)) * 8;
    offA[kc] = (wqm + l15) * 64 + x;
    offB[kc] = (wqn + l15) * 64 + x;
  }

  // staging: half = 128 rows x 8 chunks = 1024 chunks; thread covers c = i*512+tid, i=0..1
  const u16* aSrc[2][2];
  const u16* bSrc[2][2];
  int stD[2];
#pragma unroll
  for (int i = 0; i < 2; i++) {
    int c = i * 512 + tid;
    int row = c >> 3, j = (c & 7) ^ (row & 7);
    stD[i] = c * 8;
    aSrc[0][i] = A + (size_t)(m0 + row) * K + j * 8;
    aSrc[1][i] = A + (size_t)(m0 + 128 + row) * K + j * 8;
    bSrc[0][i] = BT + (size_t)(n0 + row) * K + j * 8;
    bSrc[1][i] = BT + (size_t)(n0 + 128 + row) * K + j * 8;
  }

#define STG_A(T, MH)                                                              \
  do {                                                                            \
    _Pragma("unroll")                                                             \
    for (int i_ = 0; i_ < 2; i_++)                                                \
      async_ld16(aSrc[MH][i_] + (size_t)(T) * 64,                                 \
                 &As[((MH) * 2 + ((T) & 1)) * 8192 + stD[i_]]);                   \
  } while (0)
#define STG_B(T, NH)                                                              \
  do {                                                                            \
    _Pragma("unroll")                                                             \
    for (int i_ = 0; i_ < 2; i_++)                                                \
      async_ld16(bSrc[NH][i_] + (size_t)(T) * 64,                                 \
                 &Bs[((NH) * 2 + ((T) & 1)) * 8192 + stD[i_]]);                   \
  } while (0)
#define MMQ(AV, BV, CC) CC = __builtin_amdgcn_mfma_f32_16x16x32_bf16(AV, BV, CC, 0, 0, 0)

  // phase: optionally read A frags (from AB) / B frags (from BB), issue stage stmt,
  // barrier, MFMA quadrant (MH,NH), counted vmcnt, barrier.
#define QPHASE(MH, NH, DO_RA, DO_RB, AB, BB, STGSTMT)                             \
  do {                                                                            \
    if (DO_RA) {                                                                  \
      _Pragma("unroll")                                                           \
      for (int mi = 0; mi < 4; mi++)                                              \
        _Pragma("unroll")                                                         \
        for (int kc = 0; kc < 2; kc++)                                            \
          aF[mi][kc] = *reinterpret_cast<const bf16x8*>((AB) + offA[kc] + mi * 1024); \
    }                                                                             \
    if (DO_RB) {                                                                  \
      _Pragma("unroll")                                                           \
      for (int ni = 0; ni < 2; ni++)                                              \
        _Pragma("unroll")                                                         \
        for (int kc = 0; kc < 2; kc++)                                            \
          bF[ni][kc] = *reinterpret_cast<const bf16x8*>((BB) + offB[kc] + ni * 1024); \
    }                                                                             \
    STGSTMT;                                                                      \
    raw_barrier();                                                                \
    __builtin_amdgcn_s_setprio(1);                                                \
    _Pragma("unroll")                                                             \
    for (int mi = 0; mi < 4; mi++)                                                \
      _Pragma("unroll")                                                           \
      for (int ni = 0; ni < 2; ni++) {                                            \
        MMQ(aF[mi][0], bF[ni][0], acc[(MH) * 4 + mi][(NH) * 2 + ni]);             \
        MMQ(aF[mi][1], bF[ni][1], acc[(MH) * 4 + mi][(NH) * 2 + ni]);             \
      }                                                                           \
    __builtin_amdgcn_s_setprio(0);                                                \
    if (st) wait_vmcnt<4>(); else wait_vmcnt<0>();                                \
    raw_barrier();                                                                \
  } while (0)

  f32x4 acc[8][4];
#pragma unroll
  for (int i = 0; i < 8; i++)
#pragma unroll
    for (int j = 0; j < 4; j++) acc[i][j] = (f32x4){0.f, 0.f, 0.f, 0.f};

  int NT = K >> 6;

  // prologue: tile 0's halves in steady stage order [A0,B0,B1,A1]; wait first two halves
  STG_A(0, 0);
  STG_B(0, 0);
  STG_B(0, 1);
  STG_A(0, 1);
  wait_vmcnt<4>();
  raw_barrier();

  bf16x8 aF[4][2], bF[2][2];

  for (int t = 0; t < NT; ++t) {
    const u16* A0p = &As[(t & 1) * 8192];
    const u16* A1p = &As[(2 + (t & 1)) * 8192];
    const u16* B0p = &Bs[(t & 1) * 8192];
    const u16* B1p = &Bs[(2 + (t & 1)) * 8192];
    bool st = (t + 1 < NT);

    QPHASE(0, 0, true,  true,  A0p, B0p, if (st) STG_A(t + 1, 0));
    QPHASE(0, 1, false, true,  A0p, B1p, if (st) STG_B(t + 1, 0));
    QPHASE(1, 1, true,  false, A1p, B1p, if (st) STG_B(t + 1, 1));
    QPHASE(1, 0, false, true,  A1p, B0p, if (st) STG_A(t + 1, 1));
  }
#undef QPHASE
#undef STG_A
#undef STG_B
#undef MMQ

  // epilogue: acc[i][j]: row = m0 + (i>>2)*128 + wqm + (i&3)*16 + quad*4 + r
  //                      col = n0 + (j>>1)*128 + wqn + (j&1)*16 + l15
#pragma unroll
  for (int j = 0; j < 4; j++) {
    int col = n0 + (j >> 1) * 128 + wqn + (j & 1) * 16 + l15;
    float bval = b2f(bias[col]);
#pragma unroll
    for (int i = 0; i < 8; i++) {
#pragma unroll
      for (int r = 0; r < 4; r++) {
        int row = m0 + (i >> 2) * 128 + wqm + (i & 3) * 16 + quad * 4 + r;
        float v = acc[i][j][r] + bval;
        if (GELU) v = gelu_fast(v);
        if (RES) v += b2f(res[(size_t)row * N + col]);
        if (F32OUT)
          ((float*)Cout)[(size_t)row * N + col] = v;
        else
          ((u16*)Cout)[(size_t)row * N + col] = f2b(v);
      }
    }
  }
}

// ---------------- gemm_k: 128x128 2-barrier loop (round-2 known-good; used for wo) -------
template <int GELU, int RES, int F32OUT>
__global__ __launch_bounds__(256) void gemm_k(const u16* __restrict__ A, const u16* __restrict__ BT,
                                              const u16* __restrict__ bias, const u16* __restrict__ res,
                                              void* __restrict__ Cout, int M, int N, int K) {
  __shared__ __align__(16) u16 As[128 * 64];
  __shared__ __align__(16) u16 Bs[128 * 64];
  int tid = threadIdx.x, wave = tid >> 6, lane = tid & 63;
  int l15 = lane & 15, quad = lane >> 4;
  int m0 = blockIdx.y * 128, n0 = blockIdx.x * 128;
  int wm = (wave & 1) * 64, wn = (wave >> 1) * 64;

  int offA[4][2], offB[4][2];
#pragma unroll
  for (int i = 0; i < 4; i++) {
    int rowA = wm + i * 16 + l15;
    int rowB = wn + i * 16 + l15;
#pragma unroll
    for (int kc = 0; kc < 2; kc++) {
      offA[i][kc] = rowA * 64 + (((kc * 4 + quad) ^ (rowA & 7)) * 8);
      offB[i][kc] = rowB * 64 + (((kc * 4 + quad) ^ (rowB & 7)) * 8);
    }
  }

  const u16 *aSrc[4], *bSrc[4];
  u16 *aDst[4], *bDst[4];
#pragma unroll
  for (int i = 0; i < 4; i++) {
    int c = wave * 256 + i * 64 + lane;
    int row = c >> 3;
    int j = (c & 7) ^ (row & 7);
    aSrc[i] = A + (size_t)(m0 + row) * K + j * 8;
    bSrc[i] = BT + (size_t)(n0 + row) * K + j * 8;
    aDst[i] = As + (size_t)c * 8;
    bDst[i] = Bs + (size_t)c * 8;
  }

  f32x4 acc[4][4];
#pragma unroll
  for (int mi = 0; mi < 4; mi++)
#pragma unroll
    for (int ni = 0; ni < 4; ni++) acc[mi][ni] = (f32x4){0.f, 0.f, 0.f, 0.f};

  for (int k0 = 0; k0 < K; k0 += 64) {
    __syncthreads();
#pragma unroll
    for (int i = 0; i < 4; i++) async_ld16(aSrc[i] + k0, aDst[i]);
#pragma unroll
    for (int i = 0; i < 4; i++) async_ld16(bSrc[i] + k0, bDst[i]);
    __syncthreads();
#pragma unroll
    for (int kc = 0; kc < 2; kc++) {
      bf16x8 av[4], bv[4];
#pragma unroll
      for (int i = 0; i < 4; i++) av[i] = *reinterpret_cast<const bf16x8*>(As + offA[i][kc]);
#pragma unroll
      for (int i = 0; i < 4; i++) bv[i] = *reinterpret_cast<const bf16x8*>(Bs + offB[i][kc]);
#pragma unroll
      for (int mi = 0; mi < 4; mi++)
#pragma unroll
        for (int ni = 0; ni < 4; ni++)
          acc[mi][ni] = __builtin_amdgcn_mfma_f32_16x16x32_bf16(av[mi], bv[ni], acc[mi][ni], 0, 0, 0);
    }
  }

#pragma unroll
  for (int ni = 0; ni < 4; ni++) {
    int col = n0 + wn + ni * 16 + l15;
    float bval = b2f(bias[col]);
#pragma unroll
    for (int mi = 0; mi < 4; mi++) {
#pragma unroll
      for (int r = 0; r < 4; r++) {
        int row = m0 + wm + mi * 16 + quad * 4 + r;
        float v = acc[mi][ni][r] + bval;
        if (GELU) v = gelu_fast(v);
        if (RES) v += b2f(res[(size_t)row * N + col]);
        if (F32OUT)
          ((float*)Cout)[(size_t)row * N + col] = v;
        else
          ((u16*)Cout)[(size_t)row * N + col] = f2b(v);
      }
    }
  }
}

// ---------------- gemm3: 256xBN 4-phase pipeline (round-4; used for proj K=4096) ---------
template <int BN_T, int GELU, int RES, int F32OUT>
__global__ __launch_bounds__(512, 2) void gemm3_k(const u16* __restrict__ A, const u16* __restrict__ BT,
                                                  const u16* __restrict__ bias, const u16* __restrict__ res,
                                                  void* __restrict__ Cout, int M, int N, int K) {
  constexpr int NI = BN_T / 64;
  constexpr int NB = NI;
  constexpr int AE = 256 * 64;
  constexpr int BE = BN_T * 64;

  __shared__ __align__(16) u16 As[2 * AE];
  __shared__ __align__(16) u16 Bs[2 * BE];

  int tid = threadIdx.x, wave = tid >> 6, lane = tid & 63;
  int l15 = lane & 15, quad = lane >> 4;

  int nbx = gridDim.x;
  int nwg = nbx * gridDim.y;
  int lin = blockIdx.y * nbx + blockIdx.x;
  int cpx = nwg >> 3;
  int swz = (lin & 7) * cpx + (lin >> 3);
  int m0 = (swz / nbx) * 256;
  int n0 = (swz % nbx) * BN_T;

  int wm = (wave >> 2) * 128;
  int wn = (wave & 3) * (NI * 16);

  int offA0, offA1, offB0, offB1;
  {
    int x0 = ((0 + quad) ^ (l15 & 7)) * 8;
    int x1 = ((4 + quad) ^ (l15 & 7)) * 8;
    offA0 = (wm + l15) * 64 + x0;
    offA1 = (wm + l15) * 64 + x1;
    offB0 = (wn + l15) * 64 + x0;
    offB1 = (wn + l15) * 64 + x1;
  }

  const u16* aS[4]; int aD[4];
#pragma unroll
  for (int i = 0; i < 4; i++) {
    int c = i * 512 + tid;
    int row = c >> 3, j = (c & 7) ^ (row & 7);
    aS[i] = A + (size_t)(m0 + row) * K + j * 8;
    aD[i] = c * 8;
  }
  const u16* bS[NB]; int bD[NB];
#pragma unroll
  for (int i = 0; i < NB; i++) {
    int c = i * 512 + tid;
    int row = c >> 3, j = (c & 7) ^ (row & 7);
    bS[i] = BT + (size_t)(n0 + row) * K + j * 8;
    bD[i] = c * 8;
  }

#define ISSA(T, I) async_ld16(aS[I] + (size_t)(T) * 64, &As[((T) & 1) * AE + aD[I]])
#define ISSB(T, I) async_ld16(bS[I] + (size_t)(T) * 64, &Bs[((T) & 1) * BE + bD[I]])
#define LDF(P) (*reinterpret_cast<const bf16x8*>(P))
#define MM(AV, BV, CC) CC = __builtin_amdgcn_mfma_f32_16x16x32_bf16(AV, BV, CC, 0, 0, 0)

  f32x4 acc[8][NI];
#pragma unroll
  for (int mi = 0; mi < 8; mi++)
#pragma unroll
    for (int ni = 0; ni < NI; ni++) acc[mi][ni] = (f32x4){0.f, 0.f, 0.f, 0.f};

  int NT = K >> 6;

#pragma unroll
  for (int i = 0; i < 4; i++) ISSA(0, i);
#pragma unroll
  for (int i = 0; i < NB; i++) ISSB(0, i);
#pragma unroll
  for (int i = 0; i < 4; i++) ISSA(1, i);
#pragma unroll
  for (int i = 0; i < NB; i++) ISSB(1, i);
  wait_vmcnt<4 + NB>();
  raw_barrier();

  bf16x8 bv[NI][2];

#pragma unroll 2
  for (int t = 0; t < NT; ++t) {
    const u16* Ab = &As[(t & 1) * AE];
    const u16* Bb = &Bs[(t & 1) * BE];
    bool haveN = (t >= 1) && (t + 1 < NT);
    bool haveNN = (t + 2 < NT);

    {
      bf16x8 a0 = LDF(Ab + offA0);
      bf16x8 a1 = LDF(Ab + offA0 + 1024);
      bf16x8 a2 = LDF(Ab + offA0 + 2048);
      bf16x8 a3 = LDF(Ab + offA0 + 3072);
#pragma unroll
      for (int ni = 0; ni < NI; ni++) bv[ni][0] = LDF(Bb + offB0 + ni * 1024);
      if (haveN) ISSA(t + 1, 1);
      raw_barrier();
      __builtin_amdgcn_s_setprio(1);
#pragma unroll
      for (int ni = 0; ni < NI; ni++) {
        MM(a0, bv[ni][0], acc[0][ni]);
        MM(a1, bv[ni][0], acc[1][ni]);
        MM(a2, bv[ni][0], acc[2][ni]);
        MM(a3, bv[ni][0], acc[3][ni]);
      }
      __builtin_amdgcn_s_setprio(0);
      raw_barrier();
    }
    {
      bf16x8 a0 = LDF(Ab + offA1);
      bf16x8 a1 = LDF(Ab + offA1 + 1024);
      bf16x8 a2 = LDF(Ab + offA1 + 2048);
      bf16x8 a3 = LDF(Ab + offA1 + 3072);
#pragma unroll
      for (int ni = 0; ni < NI; ni++) bv[ni][1] = LDF(Bb + offB1 + ni * 1024);
      if (haveN) ISSA(t + 1, 3);
      raw_barrier();
      __builtin_amdgcn_s_setprio(1);
#pragma unroll
      for (int ni = 0; ni < NI; ni++) {
        MM(a0, bv[ni][1], acc[0][ni]);
        MM(a1, bv[ni][1], acc[1][ni]);
        MM(a2, bv[ni][1], acc[2][ni]);
        MM(a3, bv[ni][1], acc[3][ni]);
      }
      __builtin_amdgcn_s_setprio(0);
      raw_barrier();
    }
    {
      bf16x8 a0 = LDF(Ab + offA0 + 4096);
      bf16x8 a1 = LDF(Ab + offA0 + 5120);
      bf16x8 a2 = LDF(Ab + offA0 + 6144);
      bf16x8 a3 = LDF(Ab + offA0 + 7168);
      if (haveNN) {
        ISSA(t + 2, 0);
        ISSB(t + 2, 0);
        if constexpr (NB == 4) ISSB(t + 2, 1);
      }
      raw_barrier();
      __builtin_amdgcn_s_setprio(1);
#pragma unroll
      for (int ni = 0; ni < NI; ni++) {
        MM(a0, bv[ni][0], acc[4][ni]);
        MM(a1, bv[ni][0], acc[5][ni]);
        MM(a2, bv[ni][0], acc[6][ni]);
        MM(a3, bv[ni][0], acc[7][ni]);
      }
      __builtin_amdgcn_s_setprio(0);
      raw_barrier();
    }
    {
      bf16x8 a0 = LDF(Ab + offA1 + 4096);
      bf16x8 a1 = LDF(Ab + offA1 + 5120);
      bf16x8 a2 = LDF(Ab + offA1 + 6144);
      bf16x8 a3 = LDF(Ab + offA1 + 7168);
      if (haveNN) {
        ISSA(t + 2, 2);
        if constexpr (NB == 4) { ISSB(t + 2, 2); ISSB(t + 2, 3); }
        else ISSB(t + 2, 1);
      }
      raw_barrier();
      __builtin_amdgcn_s_setprio(1);
#pragma unroll
      for (int ni = 0; ni < NI; ni++) {
        MM(a0, bv[ni][1], acc[4][ni]);
        MM(a1, bv[ni][1], acc[5][ni]);
        MM(a2, bv[ni][1], acc[6][ni]);
        MM(a3, bv[ni][1], acc[7][ni]);
      }
      __builtin_amdgcn_s_setprio(0);
      if (haveNN) wait_vmcnt<2 + NB>();
      else wait_vmcnt<0>();
      raw_barrier();
    }
  }
#undef ISSA
#undef ISSB
#undef LDF
#undef MM

#pragma unroll
  for (int ni = 0; ni < NI; ni++) {
    int col = n0 + wn + ni * 16 + l15;
    float bval = b2f(bias[col]);
#pragma unroll
    for (int mi = 0; mi < 8; mi++) {
#pragma unroll
      for (int r = 0; r < 4; r++) {
        int row = m0 + wm + mi * 16 + quad * 4 + r;
        float v = acc[mi][ni][r] + bval;
        if (GELU) v = gelu_fast(v);
        if (RES) v += b2f(res[(size_t)row * N + col]);
        if (F32OUT)
          ((float*)Cout)[(size_t)row * N + col] = v;
        else
          ((u16*)Cout)[(size_t)row * N + col] = f2b(v);
      }
    }
  }
}

// ---------------- MFMA flash attention, paired q-tiles (lo, 15-lo) ----------------
#define ATTN_PROC(QF, O, M_R, L_R, Q0, KV0, KSB)                                      \
  do {                                                                                \
    float sv[4][4];                                                                   \
    _Pragma("unroll")                                                                 \
    for (int ni = 0; ni < 4; ni++) {                                                  \
      f32x4 z = (f32x4){0.f, 0.f, 0.f, 0.f};                                          \
      _Pragma("unroll")                                                               \
      for (int kc = 0; kc < 2; kc++) {                                                \
        bf16x8 bfr = *reinterpret_cast<const bf16x8*>((KSB) + offKb[kc] + ni * 1024); \
        z = __builtin_amdgcn_mfma_f32_16x16x32_bf16(QF[kc], bfr, z, 0, 0, 0);         \
      }                                                                               \
      _Pragma("unroll")                                                               \
      for (int r = 0; r < 4; r++) sv[ni][r] = z[r];                                   \
    }                                                                                 \
    bool diag = ((KV0) + 64 > (Q0));                                                  \
    _Pragma("unroll")                                                                 \
    for (int ni = 0; ni < 4; ni++)                                                    \
      _Pragma("unroll")                                                               \
      for (int r = 0; r < 4; r++) {                                                   \
        float v = sv[ni][r] * 0.125f;                                                 \
        if (diag && ((KV0) + ni * 16 + l15 > (Q0) + quad * 4 + r)) v = -1e30f;        \
        sv[ni][r] = v;                                                                \
      }                                                                               \
    float mt[4], al[4], rs[4];                                                        \
    _Pragma("unroll")                                                                 \
    for (int r = 0; r < 4; r++) {                                                     \
      mt[r] = fmaxf(fmaxf(sv[0][r], sv[1][r]), fmaxf(sv[2][r], sv[3][r]));            \
      _Pragma("unroll")                                                               \
      for (int m = 1; m <= 8; m <<= 1) mt[r] = fmaxf(mt[r], __shfl_xor(mt[r], m, 64));\
      float mn = fmaxf(M_R[r], mt[r]);                                                \
      al[r] = __expf(M_R[r] - mn);                                                    \
      M_R[r] = mn;                                                                    \
      rs[r] = 0.f;                                                                    \
    }                                                                                 \
    _Pragma("unroll")                                                                 \
    for (int ni = 0; ni < 4; ni++)                                                    \
      _Pragma("unroll")                                                               \
      for (int r = 0; r < 4; r++) {                                                   \
        float p = __expf(sv[ni][r] - M_R[r]);                                         \
        sv[ni][r] = p;                                                                \
        rs[r] += p;                                                                   \
      }                                                                               \
    _Pragma("unroll")                                                                 \
    for (int r = 0; r < 4; r++) {                                                     \
      _Pragma("unroll")                                                               \
      for (int m = 1; m <= 8; m <<= 1) rs[r] += __shfl_xor(rs[r], m, 64);             \
      L_R[r] = L_R[r] * al[r] + rs[r];                                                \
    }                                                                                 \
    _Pragma("unroll")                                                                 \
    for (int dn = 0; dn < 4; dn++)                                                    \
      _Pragma("unroll")                                                               \
      for (int r = 0; r < 4; r++) O[dn][r] *= al[r];                                  \
    _Pragma("unroll")                                                                 \
    for (int ni = 0; ni < 4; ni++)                                                    \
      _Pragma("unroll")                                                               \
      for (int r = 0; r < 4; r++)                                                     \
        Ps[wave][pwBase + r * 72 + ni * 16] = f2b(sv[ni][r]);                         \
    _Pragma("unroll")                                                                 \
    for (int kc = 0; kc < 2; kc++) {                                                  \
      bf16x8 afr = *reinterpret_cast<const bf16x8*>(&Ps[wave][prBase + kc * 32]);     \
      _Pragma("unroll")                                                               \
      for (int dn = 0; dn < 4; dn++) {                                                \
        bf16x8 bfr = *reinterpret_cast<const bf16x8*>(&VTs[vrBase + dn * 1152 + kc * 32]); \
        O[dn] = __builtin_amdgcn_mfma_f32_16x16x32_bf16(afr, bfr, O[dn], 0, 0, 0);    \
      }                                                                               \
    }                                                                                 \
  } while (0)

__global__ __launch_bounds__(256, 4) void attn_k(const u16* __restrict__ qkv, u16* __restrict__ y) {
  int bh = blockIdx.x;
  int lo = blockIdx.y;        // 0..7
  int hi = 15 - lo;           // 15..8
  int b = bh >> 4, h = bh & 15;
  int tid = threadIdx.x, wave = tid >> 6, lane = tid & 63;
  int l15 = lane & 15, quad = lane >> 4;

  __shared__ __align__(16) u16 Ks[2][64 * 64];  // XOR-swizzled [key][chunk], dbuf
  __shared__ __align__(16) u16 VTs[64 * 72];    // [d][key], stride 72
  __shared__ __align__(16) u16 Ps[4][16 * 72];  // per-wave P [q][key], stride 72

  const u16* base = qkv + (size_t)b * Tn * 3072 + h * 64;
  int q0_lo = lo * 64 + wave * 16;
  int q0_hi = hi * 64 + wave * 16;

  bf16x8 qf_lo[2], qf_hi[2];
#pragma unroll
  for (int kc = 0; kc < 2; kc++) {
    qf_lo[kc] = *reinterpret_cast<const bf16x8*>(base + (size_t)(q0_lo + l15) * 3072 + kc * 32 + quad * 8);
    qf_hi[kc] = *reinterpret_cast<const bf16x8*>(base + (size_t)(q0_hi + l15) * 3072 + kc * 32 + quad * 8);
  }

  int offKb[2];
#pragma unroll
  for (int kc = 0; kc < 2; kc++)
    offKb[kc] = l15 * 64 + (((kc * 4 + quad) ^ (l15 & 7)) * 8);

  int kSrcOff[2], kDstOff[2];
#pragma unroll
  for (int i = 0; i < 2; i++) {
    int c = wave * 128 + i * 64 + lane;
    int row = c >> 3, j = (c & 7) ^ (row & 7);
    kSrcOff[i] = row * 3072 + j * 8;
    kDstOff[i] = c * 8;
  }
  const u16* kBase = base + 1024;
  const u16* vBase = base + 2048;
  int kp = tid & 31, dgroup = tid >> 5;
  u32* vtw = reinterpret_cast<u32*>(VTs);

#pragma unroll
  for (int i = 0; i < 2; i++) async_ld16(kBase + kSrcOff[i], &Ks[0][kDstOff[i]]);
  u16x8 va, vb;
  {
    const u16* vS = vBase + (size_t)(2 * kp) * 3072 + dgroup * 8;
    va = *reinterpret_cast<const u16x8*>(vS);
    vb = *reinterpret_cast<const u16x8*>(vS + 3072);
  }

  f32x4 o_lo[4], o_hi[4];
  float m_lo[4], l_lo[4], m_hi[4], l_hi[4];
#pragma unroll
  for (int i = 0; i < 4; i++) {
    o_lo[i] = (f32x4){0.f, 0.f, 0.f, 0.f};
    o_hi[i] = (f32x4){0.f, 0.f, 0.f, 0.f};
    m_lo[i] = -1e30f; m_hi[i] = -1e30f;
    l_lo[i] = 0.f;    l_hi[i] = 0.f;
  }

  int pwBase = quad * 4 * 72 + l15;
  int prBase = l15 * 72 + quad * 8;
  int vrBase = l15 * 72 + quad * 8;

  int kvend_hi = hi * 64, kvend_lo = lo * 64;
  int buf = 0;
  for (int kv0 = 0; kv0 <= kvend_hi; kv0 += 64) {
    __syncthreads();
#pragma unroll
    for (int i = 0; i < 8; i++)
      vtw[(dgroup * 8 + i) * 36 + kp] = (u32)va[i] | ((u32)vb[i] << 16);
    __syncthreads();
    if (kv0 + 64 <= kvend_hi) {
      const u16* kS = kBase + (size_t)(kv0 + 64) * 3072;
#pragma unroll
      for (int i = 0; i < 2; i++) async_ld16(kS + kSrcOff[i], &Ks[buf ^ 1][kDstOff[i]]);
      const u16* vS = vBase + (size_t)(kv0 + 64 + 2 * kp) * 3072 + dgroup * 8;
      va = *reinterpret_cast<const u16x8*>(vS);
      vb = *reinterpret_cast<const u16x8*>(vS + 3072);
    }
    {
      const u16* KsB = &Ks[buf][0];
      ATTN_PROC(qf_hi, o_hi, m_hi, l_hi, q0_hi, kv0, KsB);
      if (kv0 <= kvend_lo)
        ATTN_PROC(qf_lo, o_lo, m_lo, l_lo, q0_lo, kv0, KsB);
    }
    buf ^= 1;
  }

#pragma unroll
  for (int r = 0; r < 4; r++) {
    float inv = 1.0f / l_hi[r];
    int row = b * Tn + q0_hi + quad * 4 + r;
#pragma unroll
    for (int dn = 0; dn < 4; dn++)
      y[(size_t)row * Cn + h * 64 + dn * 16 + l15] = f2b(o_hi[dn][r] * inv);
  }
#pragma unroll
  for (int r = 0; r < 4; r++) {
    float inv = 1.0f / l_lo[r];
    int row = b * Tn + q0_lo + quad * 4 + r;
#pragma unroll
    for (int dn = 0; dn < 4; dn++)
      y[(size_t)row * Cn + h * 64 + dn * 16 + l15] = f2b(o_lo[dn][r] * inv);
  }
}

// ---------------- launcher ----------------
extern "C" void kernel_launch(void* const* d_in, const int* in_sizes, int n_in,
                              void* d_out, int out_size, void* d_ws, size_t ws_size,
                              hipStream_t stream) {
  const void* x      = d_in[0];
  const void* ln1_w  = d_in[1];
  const void* ln1_b  = d_in[2];
  const void* w_qkv  = d_in[3];
  const void* b_qkv  = d_in[4];
  const void* w_o    = d_in[5];
  const void* b_o    = d_in[6];
  const void* ln2_w  = d_in[7];
  const void* ln2_b  = d_in[8];
  const void* w_fc   = d_in[9];
  const void* b_fc   = d_in[10];
  const void* w_proj = d_in[11];
  const void* b_proj = d_in[12];
  const u32* flagp = (const u32*)ln1_w;

  size_t off = 0;
  char* wsb = (char*)d_ws;
  auto alloc = [&](size_t bytes) {
    void* p = wsb + off;
    off += (bytes + 255) & ~(size_t)255;
    return (u16*)p;
  };
  u16* wqkvT  = alloc((size_t)3072 * 1024 * 2);
  u16* woT    = alloc((size_t)1024 * 1024 * 2);
  u16* wfcT   = alloc((size_t)4096 * 1024 * 2);
  u16* wprojT = alloc((size_t)1024 * 4096 * 2);
  u16* xb     = alloc((size_t)Mn * 1024 * 2);
  u16* sm     = alloc((size_t)16384 * 2);
  u16* xn     = alloc((size_t)Mn * 1024 * 2);
  u16* ybuf   = alloc((size_t)Mn * 1024 * 2);
  u16* x1     = alloc((size_t)Mn * 1024 * 2);
  u16* big    = alloc((size_t)Mn * 4096 * 2);
  u16* qkvbuf = big;
  u16* hbuf   = big;
  if (off > ws_size) return;

  u16* LW1 = sm;          // 1024
  u16* LB1 = sm + 1024;   // 1024
  u16* BQKV = sm + 2048;  // 3072
  u16* BO  = sm + 5120;   // 1024
  u16* LW2 = sm + 6144;   // 1024
  u16* LB2 = sm + 7168;   // 1024
  u16* BFC = sm + 8192;   // 4096
  u16* BPJ = sm + 12288;  // 1024

  SmallCvt sc;
  sc.src[0] = ln1_w;  sc.dst[0] = LW1;  sc.n[0] = 1024;
  sc.src[1] = ln1_b;  sc.dst[1] = LB1;  sc.n[1] = 1024;
  sc.src[2] = b_qkv;  sc.dst[2] = BQKV; sc.n[2] = 3072;
  sc.src[3] = b_o;    sc.dst[3] = BO;   sc.n[3] = 1024;
  sc.src[4] = ln2_w;  sc.dst[4] = LW2;  sc.n[4] = 1024;
  sc.src[5] = ln2_b;  sc.dst[5] = LB2;  sc.n[5] = 1024;
  sc.src[6] = b_fc;   sc.dst[6] = BFC;  sc.n[6] = 4096;
  sc.src[7] = b_proj; sc.dst[7] = BPJ;  sc.n[7] = 1024;

  hipLaunchKernelGGL(cvt_small_k, dim3(52), dim3(256), 0, stream, sc, flagp);
  hipLaunchKernelGGL(cvt_x_k, dim3(Mn * 1024 / 4 / 256), dim3(256), 0, stream, x, xb, flagp);

  dim3 tb(32, 8);
  hipLaunchKernelGGL(transpose_k, dim3(3072 / 32, 1024 / 32), tb, 0, stream, w_qkv, wqkvT, 1024, 3072, flagp);
  hipLaunchKernelGGL(transpose_k, dim3(1024 / 32, 1024 / 32), tb, 0, stream, w_o, woT, 1024, 1024, flagp);
  hipLaunchKernelGGL(transpose_k, dim3(4096 / 32, 1024 / 32), tb, 0, stream, w_fc, wfcT, 1024, 4096, flagp);
  hipLaunchKernelGGL(transpose_k, dim3(1024 / 32, 4096 / 32), tb, 0, stream, w_proj, wprojT, 4096, 1024, flagp);

  hipLaunchKernelGGL(ln_k, dim3(Mn), dim3(256), 0, stream, xb, LW1, LB1, xn);
  hipLaunchKernelGGL((gemm5_k<0, 0, 0>), dim3(3072 / 256, Mn / 256), dim3(512), 0, stream,
                     xn, wqkvT, BQKV, (const u16*)nullptr, (void*)qkvbuf, Mn, 3072, 1024);
  hipLaunchKernelGGL(attn_k, dim3(Bn * Hn, 8), dim3(256), 0, stream, qkvbuf, ybuf);
  hipLaunchKernelGGL((gemm_k<0, 1, 0>), dim3(1024 / 128, Mn / 128), dim3(256), 0, stream,
                     ybuf, woT, BO, xb, (void*)x1, Mn, 1024, 1024);
  hipLaunchKernelGGL(ln_k, dim3(Mn), dim3(256), 0, stream, x1, LW2, LB2, xn);
  hipLaunchKernelGGL((gemm5_k<1, 0, 0>), dim3(4096 / 256, Mn / 256), dim3(512), 0, stream,
                     xn, wfcT, BFC, (const u16*)nullptr, (void*)hbuf, Mn, 4096, 1024);
  hipLaunchKernelGGL((gemm3_k<128, 0, 1, 1>), dim3(1024 / 128, Mn / 256), dim3(512), 0, stream,
                     hbuf, wprojT, BPJ, x1, d_out, Mn, 1024, 4096);
}

// Round 7
// 513.042 us; speedup vs baseline: 1.0671x; 1.0361x over previous
//
#include <hip/hip_runtime.h>
#include <math.h>
#include <stdint.h>

typedef unsigned short u16;
typedef unsigned int u32;
typedef __attribute__((ext_vector_type(4))) unsigned short u16x4;
typedef __attribute__((ext_vector_type(8))) unsigned short u16x8;
typedef __attribute__((ext_vector_type(8))) __bf16 bf16x8;
typedef __attribute__((ext_vector_type(4))) float f32x4;

#define Bn 8
#define Tn 1024
#define Cn 1024
#define Hn 16
#define Dn 64
#define Mn 8192   // B*T

#define F32_ONE_BITS 0x3F800000u

__device__ __forceinline__ float b2f(u16 u) {
  union { unsigned int i; float f; } v; v.i = ((unsigned int)u) << 16; return v.f;
}
__device__ __forceinline__ u16 f2b(float f) {
  union { float f; unsigned int i; } v; v.f = f;
  unsigned int r = v.i + 0x7fffu + ((v.i >> 16) & 1u);
  return (u16)(r >> 16);
}

__device__ __forceinline__ void async_ld16(const u16* g, u16* l) {
  __builtin_amdgcn_global_load_lds(
      (__attribute__((address_space(1))) void*)g,
      (__attribute__((address_space(3))) void*)l, 16, 0, 0);
}

template <int N> __device__ __forceinline__ void wait_vmcnt() {
  if constexpr (N == 8)      asm volatile("s_waitcnt vmcnt(8)" ::: "memory");
  else if constexpr (N == 6) asm volatile("s_waitcnt vmcnt(6)" ::: "memory");
  else if constexpr (N == 5) asm volatile("s_waitcnt vmcnt(5)" ::: "memory");
  else if constexpr (N == 4) asm volatile("s_waitcnt vmcnt(4)" ::: "memory");
  else if constexpr (N == 3) asm volatile("s_waitcnt vmcnt(3)" ::: "memory");
  else if constexpr (N == 2) asm volatile("s_waitcnt vmcnt(2)" ::: "memory");
  else                       asm volatile("s_waitcnt vmcnt(0)" ::: "memory");
}
__device__ __forceinline__ void raw_barrier() {
  asm volatile("s_barrier" ::: "memory");
}

// gelu_tanh(x) == x * sigmoid(2*0.79788456*(x+0.044715x^3)); one v_exp_f32, inf-safe.
__device__ __forceinline__ float gelu_fast(float x) {
  float u2 = 1.5957691216057308f * (x + 0.044715f * x * x * x);
  return x / (1.0f + __expf(-u2));
}

// ---------------- input canonicalization: fp32 -> bf16 ----------------
__global__ __launch_bounds__(256) void cvt_x_k(const void* __restrict__ src, u16* __restrict__ dst,
                                               const u32* __restrict__ flagp) {
  bool isf32 = (*flagp == F32_ONE_BITS);
  size_t i = ((size_t)blockIdx.x * 256 + threadIdx.x) * 4;
  if (isf32) {
    f32x4 v = *reinterpret_cast<const f32x4*>((const float*)src + i);
    u16x4 o;
#pragma unroll
    for (int j = 0; j < 4; j++) o[j] = f2b(v[j]);
    *reinterpret_cast<u16x4*>(dst + i) = o;
  } else {
    *reinterpret_cast<u16x4*>(dst + i) = *reinterpret_cast<const u16x4*>((const u16*)src + i);
  }
}

struct SmallCvt { const void* src[8]; u16* dst[8]; int n[8]; };

__global__ __launch_bounds__(256) void cvt_small_k(SmallCvt p, const u32* __restrict__ flagp) {
  bool isf32 = (*flagp == F32_ONE_BITS);
  int t = blockIdx.x * 256 + threadIdx.x;
  int off = 0;
#pragma unroll
  for (int i = 0; i < 8; i++) {
    int idx = t - off;
    if (idx >= 0 && idx < p.n[i]) {
      u16 v = isf32 ? f2b(((const float*)p.src[i])[idx]) : ((const u16*)p.src[i])[idx];
      p.dst[i][idx] = v;
    }
    off += p.n[i];
  }
}

// ---------------- transpose (+convert): out[n*K+k] = bf16(in[k*N+n]), in is [K][N] ----------------
__global__ __launch_bounds__(256) void transpose_k(const void* __restrict__ in,
                                                   u16* __restrict__ out, int K, int N,
                                                   const u32* __restrict__ flagp) {
  bool isf32 = (*flagp == F32_ONE_BITS);
  __shared__ u16 tile[32][33];
  int c0 = blockIdx.x * 32, r0 = blockIdx.y * 32;
  int tx = threadIdx.x, ty = threadIdx.y;  // block (32,8)
#pragma unroll
  for (int i = 0; i < 4; i++) {
    size_t idx = (size_t)(r0 + ty + i * 8) * N + c0 + tx;
    tile[ty + i * 8][tx] = isf32 ? f2b(((const float*)in)[idx]) : ((const u16*)in)[idx];
  }
  __syncthreads();
#pragma unroll
  for (int i = 0; i < 4; i++)
    out[(size_t)(c0 + ty + i * 8) * K + r0 + tx] = tile[tx][ty + i * 8];
}

// ---------------- LayerNorm over C=1024; one block (256 thr) per row ----------------
__global__ __launch_bounds__(256) void ln_k(const u16* __restrict__ x, const u16* __restrict__ w,
                                            const u16* __restrict__ bi, u16* __restrict__ out) {
  int row = blockIdx.x, tid = threadIdx.x;
  const u16* xr = x + (size_t)row * Cn;
  u16x4 xv = *reinterpret_cast<const u16x4*>(xr + tid * 4);
  float v0 = b2f(xv[0]), v1 = b2f(xv[1]), v2 = b2f(xv[2]), v3 = b2f(xv[3]);
  float s = v0 + v1 + v2 + v3;
  float s2 = v0 * v0 + v1 * v1 + v2 * v2 + v3 * v3;
#pragma unroll
  for (int m = 1; m < 64; m <<= 1) {
    s += __shfl_xor(s, m, 64);
    s2 += __shfl_xor(s2, m, 64);
  }
  __shared__ float rs_[4], rs2_[4];
  int wave = tid >> 6, lane = tid & 63;
  if (lane == 0) { rs_[wave] = s; rs2_[wave] = s2; }
  __syncthreads();
  s = rs_[0] + rs_[1] + rs_[2] + rs_[3];
  s2 = rs2_[0] + rs2_[1] + rs2_[2] + rs2_[3];
  float mu = s * (1.0f / Cn);
  float var = s2 * (1.0f / Cn) - mu * mu;
  float rstd = rsqrtf(var + 1e-5f);
  u16x4 wv = *reinterpret_cast<const u16x4*>(w + tid * 4);
  u16x4 bv = *reinterpret_cast<const u16x4*>(bi + tid * 4);
  u16x4 ov;
  float vv[4] = {v0, v1, v2, v3};
#pragma unroll
  for (int j = 0; j < 4; j++)
    ov[j] = f2b((vv[j] - mu) * rstd * b2f(wv[j]) + b2f(bv[j]));
  *reinterpret_cast<u16x4*>(out + (size_t)row * Cn + tid * 4) = ov;
}

// ---------------- gemm6: 256xBN quadrant pipeline, never-stall counted-vmcnt ledger ------
// BM=256, BN=2*NH (NH=64*NLD), BK=64, 8 waves (512 thr), 3 phases/K-tile:
//   ph0  = quadrant (0,0): read A0 frags (8 b128) + B0 frags (2*NI); MFMA 8*NI
//   ph1  = quadrant (0,1): read B1 frags (2*NI); MFMA 8*NI        (A0 frags reused)
//   ph23 = quadrants (1,1)+(1,0): read A1 frags (8); MFMA 16*NI   (B0/B1 frags reg-held)
// Stage ring (tile t+1, during tile t): ph0: A0'+B0'; ph1: B1'; ph23: A1'.
// Steady waits (loads/thread: A-half=2, B-half=NLD):
//   end ph0:  vmcnt(NLD+4)  -> retires B1(t)   [staged ph1(t-1), ~3 phases old]
//   end ph1:  vmcnt(2NLD+2) -> retires A1(t)   [staged ph23(t-1)]
//   end ph23: vmcnt(NLD+2)  -> retires A0,B0(t+1) [staged ph0(t)]
// All retired loads are >=2.5 phases (~1200+ cyc) old > HBM latency: never stalls.
// Tail (st=false): vmcnt(2)/0/0. XOR swizzle j^(row&7) on stage src + frag reads.
template <int NLD, int GELU, int RES, int F32OUT>
__global__ __launch_bounds__(512, 2) void gemm6_k(const u16* __restrict__ A, const u16* __restrict__ BT,
                                                  const u16* __restrict__ bias, const u16* __restrict__ res,
                                                  void* __restrict__ Cout, int M, int N, int K) {
  constexpr int NI = NLD;            // B frags per quadrant per wave
  constexpr int NH = 64 * NLD;       // N-half extent (128 or 64)
  constexpr int BN_T = 2 * NH;
  constexpr int AHE = 128 * 64;      // elems per A half-slot
  constexpr int BHE = NH * 64;       // elems per B half-slot

  __shared__ __align__(16) u16 As[4 * AHE];  // slot mh*2+parity
  __shared__ __align__(16) u16 Bs[4 * BHE];  // slot nh*2+parity

  int tid = threadIdx.x, wave = tid >> 6, lane = tid & 63;
  int l15 = lane & 15, quad = lane >> 4;

  // XCD-aware bijective swizzle (all grids %8==0)
  int nbx = gridDim.x;
  int nwg = nbx * gridDim.y;
  int lin = blockIdx.y * nbx + blockIdx.x;
  int cpx = nwg >> 3;
  int swz = (lin & 7) * cpx + (lin >> 3);
  int m0 = (swz / nbx) * 256;
  int n0 = (swz % nbx) * BN_T;

  int wqm = (wave >> 2) * 64;        // within-M-half row offset (0/64)
  int wqn = (wave & 3) * (16 * NI);  // within-N-half col offset

  int offA[2], offB[2];
#pragma unroll
  for (int kc = 0; kc < 2; kc++) {
    int x = ((kc * 4 + quad) ^ (l15 & 7)) * 8;
    offA[kc] = (wqm + l15) * 64 + x;
    offB[kc] = (wqn + l15) * 64 + x;
  }

  // staging addresses: A-half = 1024 chunks (2/thread); B-half = NH*8 chunks (NLD/thread)
  const u16* aSrc[2][2];
  int aD[2];
#pragma unroll
  for (int i = 0; i < 2; i++) {
    int c = i * 512 + tid;
    int row = c >> 3, j = (c & 7) ^ (row & 7);
    aD[i] = c * 8;
    aSrc[0][i] = A + (size_t)(m0 + row) * K + j * 8;
    aSrc[1][i] = A + (size_t)(m0 + 128 + row) * K + j * 8;
  }
  const u16* bSrc[2][NLD];
  int bD[NLD];
#pragma unroll
  for (int i = 0; i < NLD; i++) {
    int c = i * 512 + tid;
    int row = c >> 3, j = (c & 7) ^ (row & 7);
    bD[i] = c * 8;
    bSrc[0][i] = BT + (size_t)(n0 + row) * K + j * 8;
    bSrc[1][i] = BT + (size_t)(n0 + NH + row) * K + j * 8;
  }

#define STG_A(T, MH)                                                              \
  do {                                                                            \
    _Pragma("unroll")                                                             \
    for (int i_ = 0; i_ < 2; i_++)                                                \
      async_ld16(aSrc[MH][i_] + (size_t)(T) * 64,                                 \
                 &As[((MH) * 2 + ((T) & 1)) * AHE + aD[i_]]);                     \
  } while (0)
#define STG_B(T, NHI)                                                             \
  do {                                                                            \
    _Pragma("unroll")                                                             \
    for (int i_ = 0; i_ < NLD; i_++)                                              \
      async_ld16(bSrc[NHI][i_] + (size_t)(T) * 64,                                \
                 &Bs[((NHI) * 2 + ((T) & 1)) * BHE + bD[i_]]);                    \
  } while (0)
#define LDF(P) (*reinterpret_cast<const bf16x8*>(P))
#define MM(AV, BV, CC) CC = __builtin_amdgcn_mfma_f32_16x16x32_bf16(AV, BV, CC, 0, 0, 0)

  f32x4 acc[8][2 * NI];
#pragma unroll
  for (int i = 0; i < 8; i++)
#pragma unroll
    for (int j = 0; j < 2 * NI; j++) acc[i][j] = (f32x4){0.f, 0.f, 0.f, 0.f};

  int NT = K >> 6;

  // prologue: tile 0 in steady issue order [A0,B0,B1,A1]; retire A0,B0 only
  STG_A(0, 0);
  STG_B(0, 0);
  STG_B(0, 1);
  STG_A(0, 1);
  wait_vmcnt<NLD + 2>();
  raw_barrier();

  bf16x8 aF[4][2], bF0[NI][2], bF1[NI][2];

  for (int t = 0; t < NT; ++t) {
    int P = t & 1;
    const u16* A0p = &As[P * AHE];
    const u16* A1p = &As[(2 + P) * AHE];
    const u16* B0p = &Bs[P * BHE];
    const u16* B1p = &Bs[(2 + P) * BHE];
    bool st = (t + 1 < NT);

    // ---- ph0: quadrant (0,0) ----
#pragma unroll
    for (int mi = 0; mi < 4; mi++)
#pragma unroll
      for (int kc = 0; kc < 2; kc++) aF[mi][kc] = LDF(A0p + offA[kc] + mi * 1024);
#pragma unroll
    for (int ni = 0; ni < NI; ni++)
#pragma unroll
      for (int kc = 0; kc < 2; kc++) bF0[ni][kc] = LDF(B0p + offB[kc] + ni * 1024);
    if (st) { STG_A(t + 1, 0); STG_B(t + 1, 0); }
    raw_barrier();
    __builtin_amdgcn_s_setprio(1);
#pragma unroll
    for (int mi = 0; mi < 4; mi++)
#pragma unroll
      for (int ni = 0; ni < NI; ni++) {
        MM(aF[mi][0], bF0[ni][0], acc[mi][ni]);
        MM(aF[mi][1], bF0[ni][1], acc[mi][ni]);
      }
    __builtin_amdgcn_s_setprio(0);
    if (st) wait_vmcnt<NLD + 4>(); else wait_vmcnt<2>();
    raw_barrier();

    // ---- ph1: quadrant (0,1) ----
#pragma unroll
    for (int ni = 0; ni < NI; ni++)
#pragma unroll
      for (int kc = 0; kc < 2; kc++) bF1[ni][kc] = LDF(B1p + offB[kc] + ni * 1024);
    if (st) STG_B(t + 1, 1);
    raw_barrier();
    __builtin_amdgcn_s_setprio(1);
#pragma unroll
    for (int mi = 0; mi < 4; mi++)
#pragma unroll
      for (int ni = 0; ni < NI; ni++) {
        MM(aF[mi][0], bF1[ni][0], acc[mi][NI + ni]);
        MM(aF[mi][1], bF1[ni][1], acc[mi][NI + ni]);
      }
    __builtin_amdgcn_s_setprio(0);
    if (st) wait_vmcnt<2 * NLD + 2>(); else wait_vmcnt<0>();
    raw_barrier();

    // ---- ph23: quadrants (1,1)+(1,0) ----
#pragma unroll
    for (int mi = 0; mi < 4; mi++)
#pragma unroll
      for (int kc = 0; kc < 2; kc++) aF[mi][kc] = LDF(A1p + offA[kc] + mi * 1024);
    if (st) STG_A(t + 1, 1);
    raw_barrier();
    __builtin_amdgcn_s_setprio(1);
#pragma unroll
    for (int mi = 0; mi < 4; mi++)
#pragma unroll
      for (int ni = 0; ni < NI; ni++) {
        MM(aF[mi][0], bF1[ni][0], acc[4 + mi][NI + ni]);
        MM(aF[mi][1], bF1[ni][1], acc[4 + mi][NI + ni]);
        MM(aF[mi][0], bF0[ni][0], acc[4 + mi][ni]);
        MM(aF[mi][1], bF0[ni][1], acc[4 + mi][ni]);
      }
    __builtin_amdgcn_s_setprio(0);
    if (st) wait_vmcnt<NLD + 2>(); else wait_vmcnt<0>();
    raw_barrier();
  }
#undef STG_A
#undef STG_B
#undef LDF
#undef MM

  // epilogue: acc[i][j]: row = m0 + (i>>2)*128 + wqm + (i&3)*16 + quad*4 + r
  //                      col = n0 + (j/NI)*NH + wqn + (j%NI)*16 + l15
#pragma unroll
  for (int j = 0; j < 2 * NI; j++) {
    int col = n0 + (j / NI) * NH + wqn + (j % NI) * 16 + l15;
    float bval = b2f(bias[col]);
#pragma unroll
    for (int i = 0; i < 8; i++) {
#pragma unroll
      for (int r = 0; r < 4; r++) {
        int row = m0 + (i >> 2) * 128 + wqm + (i & 3) * 16 + quad * 4 + r;
        float v = acc[i][j][r] + bval;
        if (GELU) v = gelu_fast(v);
        if (RES) v += b2f(res[(size_t)row * N + col]);
        if (F32OUT)
          ((float*)Cout)[(size_t)row * N + col] = v;
        else
          ((u16*)Cout)[(size_t)row * N + col] = f2b(v);
      }
    }
  }
}

// ---------------- gemm_k: 128x128 2-barrier loop (round-2 known-good; used for wo) -------
template <int GELU, int RES, int F32OUT>
__global__ __launch_bounds__(256) void gemm_k(const u16* __restrict__ A, const u16* __restrict__ BT,
                                              const u16* __restrict__ bias, const u16* __restrict__ res,
                                              void* __restrict__ Cout, int M, int N, int K) {
  __shared__ __align__(16) u16 As[128 * 64];
  __shared__ __align__(16) u16 Bs[128 * 64];
  int tid = threadIdx.x, wave = tid >> 6, lane = tid & 63;
  int l15 = lane & 15, quad = lane >> 4;
  int m0 = blockIdx.y * 128, n0 = blockIdx.x * 128;
  int wm = (wave & 1) * 64, wn = (wave >> 1) * 64;

  int offA[4][2], offB[4][2];
#pragma unroll
  for (int i = 0; i < 4; i++) {
    int rowA = wm + i * 16 + l15;
    int rowB = wn + i * 16 + l15;
#pragma unroll
    for (int kc = 0; kc < 2; kc++) {
      offA[i][kc] = rowA * 64 + (((kc * 4 + quad) ^ (rowA & 7)) * 8);
      offB[i][kc] = rowB * 64 + (((kc * 4 + quad) ^ (rowB & 7)) * 8);
    }
  }

  const u16 *aSrc[4], *bSrc[4];
  u16 *aDst[4], *bDst[4];
#pragma unroll
  for (int i = 0; i < 4; i++) {
    int c = wave * 256 + i * 64 + lane;
    int row = c >> 3;
    int j = (c & 7) ^ (row & 7);
    aSrc[i] = A + (size_t)(m0 + row) * K + j * 8;
    bSrc[i] = BT + (size_t)(n0 + row) * K + j * 8;
    aDst[i] = As + (size_t)c * 8;
    bDst[i] = Bs + (size_t)c * 8;
  }

  f32x4 acc[4][4];
#pragma unroll
  for (int mi = 0; mi < 4; mi++)
#pragma unroll
    for (int ni = 0; ni < 4; ni++) acc[mi][ni] = (f32x4){0.f, 0.f, 0.f, 0.f};

  for (int k0 = 0; k0 < K; k0 += 64) {
    __syncthreads();
#pragma unroll
    for (int i = 0; i < 4; i++) async_ld16(aSrc[i] + k0, aDst[i]);
#pragma unroll
    for (int i = 0; i < 4; i++) async_ld16(bSrc[i] + k0, bDst[i]);
    __syncthreads();
#pragma unroll
    for (int kc = 0; kc < 2; kc++) {
      bf16x8 av[4], bv[4];
#pragma unroll
      for (int i = 0; i < 4; i++) av[i] = *reinterpret_cast<const bf16x8*>(As + offA[i][kc]);
#pragma unroll
      for (int i = 0; i < 4; i++) bv[i] = *reinterpret_cast<const bf16x8*>(Bs + offB[i][kc]);
#pragma unroll
      for (int mi = 0; mi < 4; mi++)
#pragma unroll
        for (int ni = 0; ni < 4; ni++)
          acc[mi][ni] = __builtin_amdgcn_mfma_f32_16x16x32_bf16(av[mi], bv[ni], acc[mi][ni], 0, 0, 0);
    }
  }

#pragma unroll
  for (int ni = 0; ni < 4; ni++) {
    int col = n0 + wn + ni * 16 + l15;
    float bval = b2f(bias[col]);
#pragma unroll
    for (int mi = 0; mi < 4; mi++) {
#pragma unroll
      for (int r = 0; r < 4; r++) {
        int row = m0 + wm + mi * 16 + quad * 4 + r;
        float v = acc[mi][ni][r] + bval;
        if (GELU) v = gelu_fast(v);
        if (RES) v += b2f(res[(size_t)row * N + col]);
        if (F32OUT)
          ((float*)Cout)[(size_t)row * N + col] = v;
        else
          ((u16*)Cout)[(size_t)row * N + col] = f2b(v);
      }
    }
  }
}

// ---------------- MFMA flash attention, paired q-tiles (lo, 15-lo) ----------------
#define ATTN_PROC(QF, O, M_R, L_R, Q0, KV0, KSB)                                      \
  do {                                                                                \
    float sv[4][4];                                                                   \
    _Pragma("unroll")                                                                 \
    for (int ni = 0; ni < 4; ni++) {                                                  \
      f32x4 z = (f32x4){0.f, 0.f, 0.f, 0.f};                                          \
      _Pragma("unroll")                                                               \
      for (int kc = 0; kc < 2; kc++) {                                                \
        bf16x8 bfr = *reinterpret_cast<const bf16x8*>((KSB) + offKb[kc] + ni * 1024); \
        z = __builtin_amdgcn_mfma_f32_16x16x32_bf16(QF[kc], bfr, z, 0, 0, 0);         \
      }                                                                               \
      _Pragma("unroll")                                                               \
      for (int r = 0; r < 4; r++) sv[ni][r] = z[r];                                   \
    }                                                                                 \
    bool diag = ((KV0) + 64 > (Q0));                                                  \
    _Pragma("unroll")                                                                 \
    for (int ni = 0; ni < 4; ni++)                                                    \
      _Pragma("unroll")                                                               \
      for (int r = 0; r < 4; r++) {                                                   \
        float v = sv[ni][r] * 0.125f;                                                 \
        if (diag && ((KV0) + ni * 16 + l15 > (Q0) + quad * 4 + r)) v = -1e30f;        \
        sv[ni][r] = v;                                                                \
      }                                                                               \
    float mt[4], al[4], rs[4];                                                        \
    _Pragma("unroll")                                                                 \
    for (int r = 0; r < 4; r++) {                                                     \
      mt[r] = fmaxf(fmaxf(sv[0][r], sv[1][r]), fmaxf(sv[2][r], sv[3][r]));            \
      _Pragma("unroll")                                                               \
      for (int m = 1; m <= 8; m <<= 1) mt[r] = fmaxf(mt[r], __shfl_xor(mt[r], m, 64));\
      float mn = fmaxf(M_R[r], mt[r]);                                                \
      al[r] = __expf(M_R[r] - mn);                                                    \
      M_R[r] = mn;                                                                    \
      rs[r] = 0.f;                                                                    \
    }                                                                                 \
    _Pragma("unroll")                                                                 \
    for (int ni = 0; ni < 4; ni++)                                                    \
      _Pragma("unroll")                                                               \
      for (int r = 0; r < 4; r++) {                                                   \
        float p = __expf(sv[ni][r] - M_R[r]);                                         \
        sv[ni][r] = p;                                                                \
        rs[r] += p;                                                                   \
      }                                                                               \
    _Pragma("unroll")                                                                 \
    for (int r = 0; r < 4; r++) {                                                     \
      _Pragma("unroll")                                                               \
      for (int m = 1; m <= 8; m <<= 1) rs[r] += __shfl_xor(rs[r], m, 64);             \
      L_R[r] = L_R[r] * al[r] + rs[r];                                                \
    }                                                                                 \
    _Pragma("unroll")                                                                 \
    for (int dn = 0; dn < 4; dn++)                                                    \
      _Pragma("unroll")                                                               \
      for (int r = 0; r < 4; r++) O[dn][r] *= al[r];                                  \
    _Pragma("unroll")                                                                 \
    for (int ni = 0; ni < 4; ni++)                                                    \
      _Pragma("unroll")                                                               \
      for (int r = 0; r < 4; r++)                                                     \
        Ps[wave][pwBase + r * 72 + ni * 16] = f2b(sv[ni][r]);                         \
    _Pragma("unroll")                                                                 \
    for (int kc = 0; kc < 2; kc++) {                                                  \
      bf16x8 afr = *reinterpret_cast<const bf16x8*>(&Ps[wave][prBase + kc * 32]);     \
      _Pragma("unroll")                                                               \
      for (int dn = 0; dn < 4; dn++) {                                                \
        bf16x8 bfr = *reinterpret_cast<const bf16x8*>(&VTs[vrBase + dn * 1152 + kc * 32]); \
        O[dn] = __builtin_amdgcn_mfma_f32_16x16x32_bf16(afr, bfr, O[dn], 0, 0, 0);    \
      }                                                                               \
    }                                                                                 \
  } while (0)

__global__ __launch_bounds__(256, 4) void attn_k(const u16* __restrict__ qkv, u16* __restrict__ y) {
  int bh = blockIdx.x;
  int lo = blockIdx.y;        // 0..7
  int hi = 15 - lo;           // 15..8
  int b = bh >> 4, h = bh & 15;
  int tid = threadIdx.x, wave = tid >> 6, lane = tid & 63;
  int l15 = lane & 15, quad = lane >> 4;

  __shared__ __align__(16) u16 Ks[2][64 * 64];  // XOR-swizzled [key][chunk], dbuf
  __shared__ __align__(16) u16 VTs[64 * 72];    // [d][key], stride 72
  __shared__ __align__(16) u16 Ps[4][16 * 72];  // per-wave P [q][key], stride 72

  const u16* base = qkv + (size_t)b * Tn * 3072 + h * 64;
  int q0_lo = lo * 64 + wave * 16;
  int q0_hi = hi * 64 + wave * 16;

  bf16x8 qf_lo[2], qf_hi[2];
#pragma unroll
  for (int kc = 0; kc < 2; kc++) {
    qf_lo[kc] = *reinterpret_cast<const bf16x8*>(base + (size_t)(q0_lo + l15) * 3072 + kc * 32 + quad * 8);
    qf_hi[kc] = *reinterpret_cast<const bf16x8*>(base + (size_t)(q0_hi + l15) * 3072 + kc * 32 + quad * 8);
  }

  int offKb[2];
#pragma unroll
  for (int kc = 0; kc < 2; kc++)
    offKb[kc] = l15 * 64 + (((kc * 4 + quad) ^ (l15 & 7)) * 8);

  int kSrcOff[2], kDstOff[2];
#pragma unroll
  for (int i = 0; i < 2; i++) {
    int c = wave * 128 + i * 64 + lane;
    int row = c >> 3, j = (c & 7) ^ (row & 7);
    kSrcOff[i] = row * 3072 + j * 8;
    kDstOff[i] = c * 8;
  }
  const u16* kBase = base + 1024;
  const u16* vBase = base + 2048;
  int kp = tid & 31, dgroup = tid >> 5;
  u32* vtw = reinterpret_cast<u32*>(VTs);

#pragma unroll
  for (int i = 0; i < 2; i++) async_ld16(kBase + kSrcOff[i], &Ks[0][kDstOff[i]]);
  u16x8 va, vb;
  {
    const u16* vS = vBase + (size_t)(2 * kp) * 3072 + dgroup * 8;
    va = *reinterpret_cast<const u16x8*>(vS);
    vb = *reinterpret_cast<const u16x8*>(vS + 3072);
  }

  f32x4 o_lo[4], o_hi[4];
  float m_lo[4], l_lo[4], m_hi[4], l_hi[4];
#pragma unroll
  for (int i = 0; i < 4; i++) {
    o_lo[i] = (f32x4){0.f, 0.f, 0.f, 0.f};
    o_hi[i] = (f32x4){0.f, 0.f, 0.f, 0.f};
    m_lo[i] = -1e30f; m_hi[i] = -1e30f;
    l_lo[i] = 0.f;    l_hi[i] = 0.f;
  }

  int pwBase = quad * 4 * 72 + l15;
  int prBase = l15 * 72 + quad * 8;
  int vrBase = l15 * 72 + quad * 8;

  int kvend_hi = hi * 64, kvend_lo = lo * 64;
  int buf = 0;
  for (int kv0 = 0; kv0 <= kvend_hi; kv0 += 64) {
    __syncthreads();
#pragma unroll
    for (int i = 0; i < 8; i++)
      vtw[(dgroup * 8 + i) * 36 + kp] = (u32)va[i] | ((u32)vb[i] << 16);
    __syncthreads();
    if (kv0 + 64 <= kvend_hi) {
      const u16* kS = kBase + (size_t)(kv0 + 64) * 3072;
#pragma unroll
      for (int i = 0; i < 2; i++) async_ld16(kS + kSrcOff[i], &Ks[buf ^ 1][kDstOff[i]]);
      const u16* vS = vBase + (size_t)(kv0 + 64 + 2 * kp) * 3072 + dgroup * 8;
      va = *reinterpret_cast<const u16x8*>(vS);
      vb = *reinterpret_cast<const u16x8*>(vS + 3072);
    }
    {
      const u16* KsB = &Ks[buf][0];
      ATTN_PROC(qf_hi, o_hi, m_hi, l_hi, q0_hi, kv0, KsB);
      if (kv0 <= kvend_lo)
        ATTN_PROC(qf_lo, o_lo, m_lo, l_lo, q0_lo, kv0, KsB);
    }
    buf ^= 1;
  }

#pragma unroll
  for (int r = 0; r < 4; r++) {
    float inv = 1.0f / l_hi[r];
    int row = b * Tn + q0_hi + quad * 4 + r;
#pragma unroll
    for (int dn = 0; dn < 4; dn++)
      y[(size_t)row * Cn + h * 64 + dn * 16 + l15] = f2b(o_hi[dn][r] * inv);
  }
#pragma unroll
  for (int r = 0; r < 4; r++) {
    float inv = 1.0f / l_lo[r];
    int row = b * Tn + q0_lo + quad * 4 + r;
#pragma unroll
    for (int dn = 0; dn < 4; dn++)
      y[(size_t)row * Cn + h * 64 + dn * 16 + l15] = f2b(o_lo[dn][r] * inv);
  }
}

// ---------------- launcher ----------------
extern "C" void kernel_launch(void* const* d_in, const int* in_sizes, int n_in,
                              void* d_out, int out_size, void* d_ws, size_t ws_size,
                              hipStream_t stream) {
  const void* x      = d_in[0];
  const void* ln1_w  = d_in[1];
  const void* ln1_b  = d_in[2];
  const void* w_qkv  = d_in[3];
  const void* b_qkv  = d_in[4];
  const void* w_o    = d_in[5];
  const void* b_o    = d_in[6];
  const void* ln2_w  = d_in[7];
  const void* ln2_b  = d_in[8];
  const void* w_fc   = d_in[9];
  const void* b_fc   = d_in[10];
  const void* w_proj = d_in[11];
  const void* b_proj = d_in[12];
  const u32* flagp = (const u32*)ln1_w;

  size_t off = 0;
  char* wsb = (char*)d_ws;
  auto alloc = [&](size_t bytes) {
    void* p = wsb + off;
    off += (bytes + 255) & ~(size_t)255;
    return (u16*)p;
  };
  u16* wqkvT  = alloc((size_t)3072 * 1024 * 2);
  u16* woT    = alloc((size_t)1024 * 1024 * 2);
  u16* wfcT   = alloc((size_t)4096 * 1024 * 2);
  u16* wprojT = alloc((size_t)1024 * 4096 * 2);
  u16* xb     = alloc((size_t)Mn * 1024 * 2);
  u16* sm     = alloc((size_t)16384 * 2);
  u16* xn     = alloc((size_t)Mn * 1024 * 2);
  u16* ybuf   = alloc((size_t)Mn * 1024 * 2);
  u16* x1     = alloc((size_t)Mn * 1024 * 2);
  u16* big    = alloc((size_t)Mn * 4096 * 2);
  u16* qkvbuf = big;
  u16* hbuf   = big;
  if (off > ws_size) return;

  u16* LW1 = sm;          // 1024
  u16* LB1 = sm + 1024;   // 1024
  u16* BQKV = sm + 2048;  // 3072
  u16* BO  = sm + 5120;   // 1024
  u16* LW2 = sm + 6144;   // 1024
  u16* LB2 = sm + 7168;   // 1024
  u16* BFC = sm + 8192;   // 4096
  u16* BPJ = sm + 12288;  // 1024

  SmallCvt sc;
  sc.src[0] = ln1_w;  sc.dst[0] = LW1;  sc.n[0] = 1024;
  sc.src[1] = ln1_b;  sc.dst[1] = LB1;  sc.n[1] = 1024;
  sc.src[2] = b_qkv;  sc.dst[2] = BQKV; sc.n[2] = 3072;
  sc.src[3] = b_o;    sc.dst[3] = BO;   sc.n[3] = 1024;
  sc.src[4] = ln2_w;  sc.dst[4] = LW2;  sc.n[4] = 1024;
  sc.src[5] = ln2_b;  sc.dst[5] = LB2;  sc.n[5] = 1024;
  sc.src[6] = b_fc;   sc.dst[6] = BFC;  sc.n[6] = 4096;
  sc.src[7] = b_proj; sc.dst[7] = BPJ;  sc.n[7] = 1024;

  hipLaunchKernelGGL(cvt_small_k, dim3(52), dim3(256), 0, stream, sc, flagp);
  hipLaunchKernelGGL(cvt_x_k, dim3(Mn * 1024 / 4 / 256), dim3(256), 0, stream, x, xb, flagp);

  dim3 tb(32, 8);
  hipLaunchKernelGGL(transpose_k, dim3(3072 / 32, 1024 / 32), tb, 0, stream, w_qkv, wqkvT, 1024, 3072, flagp);
  hipLaunchKernelGGL(transpose_k, dim3(1024 / 32, 1024 / 32), tb, 0, stream, w_o, woT, 1024, 1024, flagp);
  hipLaunchKernelGGL(transpose_k, dim3(4096 / 32, 1024 / 32), tb, 0, stream, w_fc, wfcT, 1024, 4096, flagp);
  hipLaunchKernelGGL(transpose_k, dim3(1024 / 32, 4096 / 32), tb, 0, stream, w_proj, wprojT, 4096, 1024, flagp);

  hipLaunchKernelGGL(ln_k, dim3(Mn), dim3(256), 0, stream, xb, LW1, LB1, xn);
  hipLaunchKernelGGL((gemm6_k<1, 0, 0, 0>), dim3(3072 / 128, Mn / 256), dim3(512), 0, stream,
                     xn, wqkvT, BQKV, (const u16*)nullptr, (void*)qkvbuf, Mn, 3072, 1024);
  hipLaunchKernelGGL(attn_k, dim3(Bn * Hn, 8), dim3(256), 0, stream, qkvbuf, ybuf);
  hipLaunchKernelGGL((gemm_k<0, 1, 0>), dim3(1024 / 128, Mn / 128), dim3(256), 0, stream,
                     ybuf, woT, BO, xb, (void*)x1, Mn, 1024, 1024);
  hipLaunchKernelGGL(ln_k, dim3(Mn), dim3(256), 0, stream, x1, LW2, LB2, xn);
  hipLaunchKernelGGL((gemm6_k<2, 1, 0, 0>), dim3(4096 / 256, Mn / 256), dim3(512), 0, stream,
                     xn, wfcT, BFC, (const u16*)nullptr, (void*)hbuf, Mn, 4096, 1024);
  hipLaunchKernelGGL((gemm6_k<1, 0, 1, 1>), dim3(1024 / 128, Mn / 256), dim3(512), 0, stream,
                     hbuf, wprojT, BPJ, x1, d_out, Mn, 1024, 4096);
}

// Round 8
// 501.435 us; speedup vs baseline: 1.0918x; 1.0231x over previous
//
#include <hip/hip_runtime.h>
#include <math.h>
#include <stdint.h>

typedef unsigned short u16;
typedef unsigned int u32;
typedef __attribute__((ext_vector_type(4))) unsigned short u16x4;
typedef __attribute__((ext_vector_type(8))) unsigned short u16x8;
typedef __attribute__((ext_vector_type(8))) __bf16 bf16x8;
typedef __attribute__((ext_vector_type(4))) float f32x4;

#define Bn 8
#define Tn 1024
#define Cn 1024
#define Hn 16
#define Dn 64
#define Mn 8192   // B*T

#define F32_ONE_BITS 0x3F800000u

__device__ __forceinline__ float b2f(u16 u) {
  union { unsigned int i; float f; } v; v.i = ((unsigned int)u) << 16; return v.f;
}
__device__ __forceinline__ u16 f2b(float f) {
  union { float f; unsigned int i; } v; v.f = f;
  unsigned int r = v.i + 0x7fffu + ((v.i >> 16) & 1u);
  return (u16)(r >> 16);
}

__device__ __forceinline__ void async_ld16(const u16* g, u16* l) {
  __builtin_amdgcn_global_load_lds(
      (__attribute__((address_space(1))) void*)g,
      (__attribute__((address_space(3))) void*)l, 16, 0, 0);
}

template <int N> __device__ __forceinline__ void wait_vmcnt() {
  if constexpr (N == 8)      asm volatile("s_waitcnt vmcnt(8)" ::: "memory");
  else if constexpr (N == 6) asm volatile("s_waitcnt vmcnt(6)" ::: "memory");
  else if constexpr (N == 5) asm volatile("s_waitcnt vmcnt(5)" ::: "memory");
  else if constexpr (N == 4) asm volatile("s_waitcnt vmcnt(4)" ::: "memory");
  else if constexpr (N == 3) asm volatile("s_waitcnt vmcnt(3)" ::: "memory");
  else if constexpr (N == 2) asm volatile("s_waitcnt vmcnt(2)" ::: "memory");
  else                       asm volatile("s_waitcnt vmcnt(0)" ::: "memory");
}
__device__ __forceinline__ void raw_barrier() {
  asm volatile("s_barrier" ::: "memory");
}

// gelu_tanh(x) == x * sigmoid(2*0.79788456*(x+0.044715x^3)); one v_exp_f32, inf-safe.
__device__ __forceinline__ float gelu_fast(float x) {
  float u2 = 1.5957691216057308f * (x + 0.044715f * x * x * x);
  return x / (1.0f + __expf(-u2));
}

struct SmallCvt { const void* src[8]; u16* dst[8]; int n[8]; };

__global__ __launch_bounds__(256) void cvt_small_k(SmallCvt p, const u32* __restrict__ flagp) {
  bool isf32 = (*flagp == F32_ONE_BITS);
  int t = blockIdx.x * 256 + threadIdx.x;
  int off = 0;
#pragma unroll
  for (int i = 0; i < 8; i++) {
    int idx = t - off;
    if (idx >= 0 && idx < p.n[i]) {
      u16 v = isf32 ? f2b(((const float*)p.src[i])[idx]) : ((const u16*)p.src[i])[idx];
      p.dst[i][idx] = v;
    }
    off += p.n[i];
  }
}

// ---------------- fused input cvt (fp32->bf16) + LayerNorm1; one block per row ----------
// Writes xb (bf16 copy of x, residual for wo-gemm) AND xn (LN1 output) in one pass.
// LN stats computed on the bf16-ROUNDED values (bit-identical to prior cvt_x_k + ln_k).
__global__ __launch_bounds__(256) void cvtln_k(const void* __restrict__ src,
                                               const u16* __restrict__ w, const u16* __restrict__ bi,
                                               u16* __restrict__ xb, u16* __restrict__ xn,
                                               const u32* __restrict__ flagp) {
  bool isf32 = (*flagp == F32_ONE_BITS);
  int row = blockIdx.x, tid = threadIdx.x;
  size_t base = (size_t)row * Cn + tid * 4;
  u16x4 xv;
  if (isf32) {
    f32x4 v = *reinterpret_cast<const f32x4*>((const float*)src + base);
#pragma unroll
    for (int j = 0; j < 4; j++) xv[j] = f2b(v[j]);
  } else {
    xv = *reinterpret_cast<const u16x4*>((const u16*)src + base);
  }
  *reinterpret_cast<u16x4*>(xb + base) = xv;

  float v0 = b2f(xv[0]), v1 = b2f(xv[1]), v2 = b2f(xv[2]), v3 = b2f(xv[3]);
  float s = v0 + v1 + v2 + v3;
  float s2 = v0 * v0 + v1 * v1 + v2 * v2 + v3 * v3;
#pragma unroll
  for (int m = 1; m < 64; m <<= 1) {
    s += __shfl_xor(s, m, 64);
    s2 += __shfl_xor(s2, m, 64);
  }
  __shared__ float rs_[4], rs2_[4];
  int wave = tid >> 6, lane = tid & 63;
  if (lane == 0) { rs_[wave] = s; rs2_[wave] = s2; }
  __syncthreads();
  s = rs_[0] + rs_[1] + rs_[2] + rs_[3];
  s2 = rs2_[0] + rs2_[1] + rs2_[2] + rs2_[3];
  float mu = s * (1.0f / Cn);
  float var = s2 * (1.0f / Cn) - mu * mu;
  float rstd = rsqrtf(var + 1e-5f);
  u16x4 wv = *reinterpret_cast<const u16x4*>(w + tid * 4);
  u16x4 bv = *reinterpret_cast<const u16x4*>(bi + tid * 4);
  u16x4 ov;
  float vv[4] = {v0, v1, v2, v3};
#pragma unroll
  for (int j = 0; j < 4; j++)
    ov[j] = f2b((vv[j] - mu) * rstd * b2f(wv[j]) + b2f(bv[j]));
  *reinterpret_cast<u16x4*>(xn + base) = ov;
}

// ---------------- transpose (+convert): out[n*K+k] = bf16(in[k*N+n]), in is [K][N] ----------------
__global__ __launch_bounds__(256) void transpose_k(const void* __restrict__ in,
                                                   u16* __restrict__ out, int K, int N,
                                                   const u32* __restrict__ flagp) {
  bool isf32 = (*flagp == F32_ONE_BITS);
  __shared__ u16 tile[32][33];
  int c0 = blockIdx.x * 32, r0 = blockIdx.y * 32;
  int tx = threadIdx.x, ty = threadIdx.y;  // block (32,8)
#pragma unroll
  for (int i = 0; i < 4; i++) {
    size_t idx = (size_t)(r0 + ty + i * 8) * N + c0 + tx;
    tile[ty + i * 8][tx] = isf32 ? f2b(((const float*)in)[idx]) : ((const u16*)in)[idx];
  }
  __syncthreads();
#pragma unroll
  for (int i = 0; i < 4; i++)
    out[(size_t)(c0 + ty + i * 8) * K + r0 + tx] = tile[tx][ty + i * 8];
}

// ---------------- LayerNorm over C=1024; one block (256 thr) per row ----------------
__global__ __launch_bounds__(256) void ln_k(const u16* __restrict__ x, const u16* __restrict__ w,
                                            const u16* __restrict__ bi, u16* __restrict__ out) {
  int row = blockIdx.x, tid = threadIdx.x;
  const u16* xr = x + (size_t)row * Cn;
  u16x4 xv = *reinterpret_cast<const u16x4*>(xr + tid * 4);
  float v0 = b2f(xv[0]), v1 = b2f(xv[1]), v2 = b2f(xv[2]), v3 = b2f(xv[3]);
  float s = v0 + v1 + v2 + v3;
  float s2 = v0 * v0 + v1 * v1 + v2 * v2 + v3 * v3;
#pragma unroll
  for (int m = 1; m < 64; m <<= 1) {
    s += __shfl_xor(s, m, 64);
    s2 += __shfl_xor(s2, m, 64);
  }
  __shared__ float rs_[4], rs2_[4];
  int wave = tid >> 6, lane = tid & 63;
  if (lane == 0) { rs_[wave] = s; rs2_[wave] = s2; }
  __syncthreads();
  s = rs_[0] + rs_[1] + rs_[2] + rs_[3];
  s2 = rs2_[0] + rs2_[1] + rs2_[2] + rs2_[3];
  float mu = s * (1.0f / Cn);
  float var = s2 * (1.0f / Cn) - mu * mu;
  float rstd = rsqrtf(var + 1e-5f);
  u16x4 wv = *reinterpret_cast<const u16x4*>(w + tid * 4);
  u16x4 bv = *reinterpret_cast<const u16x4*>(bi + tid * 4);
  u16x4 ov;
  float vv[4] = {v0, v1, v2, v3};
#pragma unroll
  for (int j = 0; j < 4; j++)
    ov[j] = f2b((vv[j] - mu) * rstd * b2f(wv[j]) + b2f(bv[j]));
  *reinterpret_cast<u16x4*>(out + (size_t)row * Cn + tid * 4) = ov;
}

// ---------------- gemm6: 256xBN quadrant pipeline, never-stall counted-vmcnt ledger ------
// (unchanged from round 7 — best measured: fc 91 us @ MfmaUtil 31%)
template <int NLD, int GELU, int RES, int F32OUT>
__global__ __launch_bounds__(512, 2) void gemm6_k(const u16* __restrict__ A, const u16* __restrict__ BT,
                                                  const u16* __restrict__ bias, const u16* __restrict__ res,
                                                  void* __restrict__ Cout, int M, int N, int K) {
  constexpr int NI = NLD;            // B frags per quadrant per wave
  constexpr int NH = 64 * NLD;       // N-half extent (128 or 64)
  constexpr int BN_T = 2 * NH;
  constexpr int AHE = 128 * 64;      // elems per A half-slot
  constexpr int BHE = NH * 64;       // elems per B half-slot

  __shared__ __align__(16) u16 As[4 * AHE];  // slot mh*2+parity
  __shared__ __align__(16) u16 Bs[4 * BHE];  // slot nh*2+parity

  int tid = threadIdx.x, wave = tid >> 6, lane = tid & 63;
  int l15 = lane & 15, quad = lane >> 4;

  // XCD-aware bijective swizzle (all grids %8==0)
  int nbx = gridDim.x;
  int nwg = nbx * gridDim.y;
  int lin = blockIdx.y * nbx + blockIdx.x;
  int cpx = nwg >> 3;
  int swz = (lin & 7) * cpx + (lin >> 3);
  int m0 = (swz / nbx) * 256;
  int n0 = (swz % nbx) * BN_T;

  int wqm = (wave >> 2) * 64;        // within-M-half row offset (0/64)
  int wqn = (wave & 3) * (16 * NI);  // within-N-half col offset

  int offA[2], offB[2];
#pragma unroll
  for (int kc = 0; kc < 2; kc++) {
    int x = ((kc * 4 + quad) ^ (l15 & 7)) * 8;
    offA[kc] = (wqm + l15) * 64 + x;
    offB[kc] = (wqn + l15) * 64 + x;
  }

  // staging addresses: A-half = 1024 chunks (2/thread); B-half = NH*8 chunks (NLD/thread)
  const u16* aSrc[2][2];
  int aD[2];
#pragma unroll
  for (int i = 0; i < 2; i++) {
    int c = i * 512 + tid;
    int row = c >> 3, j = (c & 7) ^ (row & 7);
    aD[i] = c * 8;
    aSrc[0][i] = A + (size_t)(m0 + row) * K + j * 8;
    aSrc[1][i] = A + (size_t)(m0 + 128 + row) * K + j * 8;
  }
  const u16* bSrc[2][NLD];
  int bD[NLD];
#pragma unroll
  for (int i = 0; i < NLD; i++) {
    int c = i * 512 + tid;
    int row = c >> 3, j = (c & 7) ^ (row & 7);
    bD[i] = c * 8;
    bSrc[0][i] = BT + (size_t)(n0 + row) * K + j * 8;
    bSrc[1][i] = BT + (size_t)(n0 + NH + row) * K + j * 8;
  }

#define STG_A(T, MH)                                                              \
  do {                                                                            \
    _Pragma("unroll")                                                             \
    for (int i_ = 0; i_ < 2; i_++)                                                \
      async_ld16(aSrc[MH][i_] + (size_t)(T) * 64,                                 \
                 &As[((MH) * 2 + ((T) & 1)) * AHE + aD[i_]]);                     \
  } while (0)
#define STG_B(T, NHI)                                                             \
  do {                                                                            \
    _Pragma("unroll")                                                             \
    for (int i_ = 0; i_ < NLD; i_++)                                              \
      async_ld16(bSrc[NHI][i_] + (size_t)(T) * 64,                                \
                 &Bs[((NHI) * 2 + ((T) & 1)) * BHE + bD[i_]]);                    \
  } while (0)
#define LDF(P) (*reinterpret_cast<const bf16x8*>(P))
#define MM(AV, BV, CC) CC = __builtin_amdgcn_mfma_f32_16x16x32_bf16(AV, BV, CC, 0, 0, 0)

  f32x4 acc[8][2 * NI];
#pragma unroll
  for (int i = 0; i < 8; i++)
#pragma unroll
    for (int j = 0; j < 2 * NI; j++) acc[i][j] = (f32x4){0.f, 0.f, 0.f, 0.f};

  int NT = K >> 6;

  // prologue: tile 0 in steady issue order [A0,B0,B1,A1]; retire A0,B0 only
  STG_A(0, 0);
  STG_B(0, 0);
  STG_B(0, 1);
  STG_A(0, 1);
  wait_vmcnt<NLD + 2>();
  raw_barrier();

  bf16x8 aF[4][2], bF0[NI][2], bF1[NI][2];

  for (int t = 0; t < NT; ++t) {
    int P = t & 1;
    const u16* A0p = &As[P * AHE];
    const u16* A1p = &As[(2 + P) * AHE];
    const u16* B0p = &Bs[P * BHE];
    const u16* B1p = &Bs[(2 + P) * BHE];
    bool st = (t + 1 < NT);

    // ---- ph0: quadrant (0,0) ----
#pragma unroll
    for (int mi = 0; mi < 4; mi++)
#pragma unroll
      for (int kc = 0; kc < 2; kc++) aF[mi][kc] = LDF(A0p + offA[kc] + mi * 1024);
#pragma unroll
    for (int ni = 0; ni < NI; ni++)
#pragma unroll
      for (int kc = 0; kc < 2; kc++) bF0[ni][kc] = LDF(B0p + offB[kc] + ni * 1024);
    if (st) { STG_A(t + 1, 0); STG_B(t + 1, 0); }
    raw_barrier();
    __builtin_amdgcn_s_setprio(1);
#pragma unroll
    for (int mi = 0; mi < 4; mi++)
#pragma unroll
      for (int ni = 0; ni < NI; ni++) {
        MM(aF[mi][0], bF0[ni][0], acc[mi][ni]);
        MM(aF[mi][1], bF0[ni][1], acc[mi][ni]);
      }
    __builtin_amdgcn_s_setprio(0);
    if (st) wait_vmcnt<NLD + 4>(); else wait_vmcnt<2>();
    raw_barrier();

    // ---- ph1: quadrant (0,1) ----
#pragma unroll
    for (int ni = 0; ni < NI; ni++)
#pragma unroll
      for (int kc = 0; kc < 2; kc++) bF1[ni][kc] = LDF(B1p + offB[kc] + ni * 1024);
    if (st) STG_B(t + 1, 1);
    raw_barrier();
    __builtin_amdgcn_s_setprio(1);
#pragma unroll
    for (int mi = 0; mi < 4; mi++)
#pragma unroll
      for (int ni = 0; ni < NI; ni++) {
        MM(aF[mi][0], bF1[ni][0], acc[mi][NI + ni]);
        MM(aF[mi][1], bF1[ni][1], acc[mi][NI + ni]);
      }
    __builtin_amdgcn_s_setprio(0);
    if (st) wait_vmcnt<2 * NLD + 2>(); else wait_vmcnt<0>();
    raw_barrier();

    // ---- ph23: quadrants (1,1)+(1,0) ----
#pragma unroll
    for (int mi = 0; mi < 4; mi++)
#pragma unroll
      for (int kc = 0; kc < 2; kc++) aF[mi][kc] = LDF(A1p + offA[kc] + mi * 1024);
    if (st) STG_A(t + 1, 1);
    raw_barrier();
    __builtin_amdgcn_s_setprio(1);
#pragma unroll
    for (int mi = 0; mi < 4; mi++)
#pragma unroll
      for (int ni = 0; ni < NI; ni++) {
        MM(aF[mi][0], bF1[ni][0], acc[4 + mi][NI + ni]);
        MM(aF[mi][1], bF1[ni][1], acc[4 + mi][NI + ni]);
        MM(aF[mi][0], bF0[ni][0], acc[4 + mi][ni]);
        MM(aF[mi][1], bF0[ni][1], acc[4 + mi][ni]);
      }
    __builtin_amdgcn_s_setprio(0);
    if (st) wait_vmcnt<NLD + 2>(); else wait_vmcnt<0>();
    raw_barrier();
  }
#undef STG_A
#undef STG_B
#undef LDF
#undef MM

  // epilogue: acc[i][j]: row = m0 + (i>>2)*128 + wqm + (i&3)*16 + quad*4 + r
  //                      col = n0 + (j/NI)*NH + wqn + (j%NI)*16 + l15
#pragma unroll
  for (int j = 0; j < 2 * NI; j++) {
    int col = n0 + (j / NI) * NH + wqn + (j % NI) * 16 + l15;
    float bval = b2f(bias[col]);
#pragma unroll
    for (int i = 0; i < 8; i++) {
#pragma unroll
      for (int r = 0; r < 4; r++) {
        int row = m0 + (i >> 2) * 128 + wqm + (i & 3) * 16 + quad * 4 + r;
        float v = acc[i][j][r] + bval;
        if (GELU) v = gelu_fast(v);
        if (RES) v += b2f(res[(size_t)row * N + col]);
        if (F32OUT)
          ((float*)Cout)[(size_t)row * N + col] = v;
        else
          ((u16*)Cout)[(size_t)row * N + col] = f2b(v);
      }
    }
  }
}

// ---------------- gemm_k: 128x128 2-barrier loop (round-2 known-good; used for wo) -------
template <int GELU, int RES, int F32OUT>
__global__ __launch_bounds__(256) void gemm_k(const u16* __restrict__ A, const u16* __restrict__ BT,
                                              const u16* __restrict__ bias, const u16* __restrict__ res,
                                              void* __restrict__ Cout, int M, int N, int K) {
  __shared__ __align__(16) u16 As[128 * 64];
  __shared__ __align__(16) u16 Bs[128 * 64];
  int tid = threadIdx.x, wave = tid >> 6, lane = tid & 63;
  int l15 = lane & 15, quad = lane >> 4;
  int m0 = blockIdx.y * 128, n0 = blockIdx.x * 128;
  int wm = (wave & 1) * 64, wn = (wave >> 1) * 64;

  int offA[4][2], offB[4][2];
#pragma unroll
  for (int i = 0; i < 4; i++) {
    int rowA = wm + i * 16 + l15;
    int rowB = wn + i * 16 + l15;
#pragma unroll
    for (int kc = 0; kc < 2; kc++) {
      offA[i][kc] = rowA * 64 + (((kc * 4 + quad) ^ (rowA & 7)) * 8);
      offB[i][kc] = rowB * 64 + (((kc * 4 + quad) ^ (rowB & 7)) * 8);
    }
  }

  const u16 *aSrc[4], *bSrc[4];
  u16 *aDst[4], *bDst[4];
#pragma unroll
  for (int i = 0; i < 4; i++) {
    int c = wave * 256 + i * 64 + lane;
    int row = c >> 3;
    int j = (c & 7) ^ (row & 7);
    aSrc[i] = A + (size_t)(m0 + row) * K + j * 8;
    bSrc[i] = BT + (size_t)(n0 + row) * K + j * 8;
    aDst[i] = As + (size_t)c * 8;
    bDst[i] = Bs + (size_t)c * 8;
  }

  f32x4 acc[4][4];
#pragma unroll
  for (int mi = 0; mi < 4; mi++)
#pragma unroll
    for (int ni = 0; ni < 4; ni++) acc[mi][ni] = (f32x4){0.f, 0.f, 0.f, 0.f};

  for (int k0 = 0; k0 < K; k0 += 64) {
    __syncthreads();
#pragma unroll
    for (int i = 0; i < 4; i++) async_ld16(aSrc[i] + k0, aDst[i]);
#pragma unroll
    for (int i = 0; i < 4; i++) async_ld16(bSrc[i] + k0, bDst[i]);
    __syncthreads();
#pragma unroll
    for (int kc = 0; kc < 2; kc++) {
      bf16x8 av[4], bv[4];
#pragma unroll
      for (int i = 0; i < 4; i++) av[i] = *reinterpret_cast<const bf16x8*>(As + offA[i][kc]);
#pragma unroll
      for (int i = 0; i < 4; i++) bv[i] = *reinterpret_cast<const bf16x8*>(Bs + offB[i][kc]);
#pragma unroll
      for (int mi = 0; mi < 4; mi++)
#pragma unroll
        for (int ni = 0; ni < 4; ni++)
          acc[mi][ni] = __builtin_amdgcn_mfma_f32_16x16x32_bf16(av[mi], bv[ni], acc[mi][ni], 0, 0, 0);
    }
  }

#pragma unroll
  for (int ni = 0; ni < 4; ni++) {
    int col = n0 + wn + ni * 16 + l15;
    float bval = b2f(bias[col]);
#pragma unroll
    for (int mi = 0; mi < 4; mi++) {
#pragma unroll
      for (int r = 0; r < 4; r++) {
        int row = m0 + wm + mi * 16 + quad * 4 + r;
        float v = acc[mi][ni][r] + bval;
        if (GELU) v = gelu_fast(v);
        if (RES) v += b2f(res[(size_t)row * N + col]);
        if (F32OUT)
          ((float*)Cout)[(size_t)row * N + col] = v;
        else
          ((u16*)Cout)[(size_t)row * N + col] = f2b(v);
      }
    }
  }
}

// ---------------- MFMA flash attention, paired q-tiles (lo, 15-lo) ----------------
// log2-domain softmax: scores scaled once by 0.125*log2(e); exp2f = bare v_exp_f32
// (removes the hidden log2e multiply inside every __expf: ~40 VALU/PROC).
#define ATTN_SC 0.18033688011112042f
#define ATTN_PROC(QF, O, M_R, L_R, Q0, KV0, KSB)                                      \
  do {                                                                                \
    float sv[4][4];                                                                   \
    _Pragma("unroll")                                                                 \
    for (int ni = 0; ni < 4; ni++) {                                                  \
      f32x4 z = (f32x4){0.f, 0.f, 0.f, 0.f};                                          \
      _Pragma("unroll")                                                               \
      for (int kc = 0; kc < 2; kc++) {                                                \
        bf16x8 bfr = *reinterpret_cast<const bf16x8*>((KSB) + offKb[kc] + ni * 1024); \
        z = __builtin_amdgcn_mfma_f32_16x16x32_bf16(QF[kc], bfr, z, 0, 0, 0);         \
      }                                                                               \
      _Pragma("unroll")                                                               \
      for (int r = 0; r < 4; r++) sv[ni][r] = z[r];                                   \
    }                                                                                 \
    bool diag = ((KV0) + 64 > (Q0));                                                  \
    _Pragma("unroll")                                                                 \
    for (int ni = 0; ni < 4; ni++)                                                    \
      _Pragma("unroll")                                                               \
      for (int r = 0; r < 4; r++) {                                                   \
        float v = sv[ni][r] * ATTN_SC;                                                \
        if (diag && ((KV0) + ni * 16 + l15 > (Q0) + quad * 4 + r)) v = -1e30f;        \
        sv[ni][r] = v;                                                                \
      }                                                                               \
    float mt[4], al[4], rs[4];                                                        \
    _Pragma("unroll")                                                                 \
    for (int r = 0; r < 4; r++) {                                                     \
      mt[r] = fmaxf(fmaxf(sv[0][r], sv[1][r]), fmaxf(sv[2][r], sv[3][r]));            \
      _Pragma("unroll")                                                               \
      for (int m = 1; m <= 8; m <<= 1) mt[r] = fmaxf(mt[r], __shfl_xor(mt[r], m, 64));\
      float mn = fmaxf(M_R[r], mt[r]);                                                \
      al[r] = exp2f(M_R[r] - mn);                                                     \
      M_R[r] = mn;                                                                    \
      rs[r] = 0.f;                                                                    \
    }                                                                                 \
    _Pragma("unroll")                                                                 \
    for (int ni = 0; ni < 4; ni++)                                                    \
      _Pragma("unroll")                                                               \
      for (int r = 0; r < 4; r++) {                                                   \
        float p = exp2f(sv[ni][r] - M_R[r]);                                          \
        sv[ni][r] = p;                                                                \
        rs[r] += p;                                                                   \
      }                                                                               \
    _Pragma("unroll")                                                                 \
    for (int r = 0; r < 4; r++) {                                                     \
      _Pragma("unroll")                                                               \
      for (int m = 1; m <= 8; m <<= 1) rs[r] += __shfl_xor(rs[r], m, 64);             \
      L_R[r] = L_R[r] * al[r] + rs[r];                                                \
    }                                                                                 \
    _Pragma("unroll")                                                                 \
    for (int dn = 0; dn < 4; dn++)                                                    \
      _Pragma("unroll")                                                               \
      for (int r = 0; r < 4; r++) O[dn][r] *= al[r];                                  \
    _Pragma("unroll")                                                                 \
    for (int ni = 0; ni < 4; ni++)                                                    \
      _Pragma("unroll")                                                               \
      for (int r = 0; r < 4; r++)                                                     \
        Ps[wave][pwBase + r * 72 + ni * 16] = f2b(sv[ni][r]);                         \
    _Pragma("unroll")                                                                 \
    for (int kc = 0; kc < 2; kc++) {                                                  \
      bf16x8 afr = *reinterpret_cast<const bf16x8*>(&Ps[wave][prBase + kc * 32]);     \
      _Pragma("unroll")                                                               \
      for (int dn = 0; dn < 4; dn++) {                                                \
        bf16x8 bfr = *reinterpret_cast<const bf16x8*>(&VTs[vrBase + dn * 1152 + kc * 32]); \
        O[dn] = __builtin_amdgcn_mfma_f32_16x16x32_bf16(afr, bfr, O[dn], 0, 0, 0);    \
      }                                                                               \
    }                                                                                 \
  } while (0)

__global__ __launch_bounds__(256, 4) void attn_k(const u16* __restrict__ qkv, u16* __restrict__ y) {
  int bh = blockIdx.x;
  int lo = blockIdx.y;        // 0..7
  int hi = 15 - lo;           // 15..8
  int b = bh >> 4, h = bh & 15;
  int tid = threadIdx.x, wave = tid >> 6, lane = tid & 63;
  int l15 = lane & 15, quad = lane >> 4;

  __shared__ __align__(16) u16 Ks[2][64 * 64];  // XOR-swizzled [key][chunk], dbuf
  __shared__ __align__(16) u16 VTs[64 * 72];    // [d][key], stride 72
  __shared__ __align__(16) u16 Ps[4][16 * 72];  // per-wave P [q][key], stride 72

  const u16* base = qkv + (size_t)b * Tn * 3072 + h * 64;
  int q0_lo = lo * 64 + wave * 16;
  int q0_hi = hi * 64 + wave * 16;

  bf16x8 qf_lo[2], qf_hi[2];
#pragma unroll
  for (int kc = 0; kc < 2; kc++) {
    qf_lo[kc] = *reinterpret_cast<const bf16x8*>(base + (size_t)(q0_lo + l15) * 3072 + kc * 32 + quad * 8);
    qf_hi[kc] = *reinterpret_cast<const bf16x8*>(base + (size_t)(q0_hi + l15) * 3072 + kc * 32 + quad * 8);
  }

  int offKb[2];
#pragma unroll
  for (int kc = 0; kc < 2; kc++)
    offKb[kc] = l15 * 64 + (((kc * 4 + quad) ^ (l15 & 7)) * 8);

  int kSrcOff[2], kDstOff[2];
#pragma unroll
  for (int i = 0; i < 2; i++) {
    int c = wave * 128 + i * 64 + lane;
    int row = c >> 3, j = (c & 7) ^ (row & 7);
    kSrcOff[i] = row * 3072 + j * 8;
    kDstOff[i] = c * 8;
  }
  const u16* kBase = base + 1024;
  const u16* vBase = base + 2048;
  int kp = tid & 31, dgroup = tid >> 5;
  u32* vtw = reinterpret_cast<u32*>(VTs);

#pragma unroll
  for (int i = 0; i < 2; i++) async_ld16(kBase + kSrcOff[i], &Ks[0][kDstOff[i]]);
  u16x8 va, vb;
  {
    const u16* vS = vBase + (size_t)(2 * kp) * 3072 + dgroup * 8;
    va = *reinterpret_cast<const u16x8*>(vS);
    vb = *reinterpret_cast<const u16x8*>(vS + 3072);
  }

  f32x4 o_lo[4], o_hi[4];
  float m_lo[4], l_lo[4], m_hi[4], l_hi[4];
#pragma unroll
  for (int i = 0; i < 4; i++) {
    o_lo[i] = (f32x4){0.f, 0.f, 0.f, 0.f};
    o_hi[i] = (f32x4){0.f, 0.f, 0.f, 0.f};
    m_lo[i] = -1e30f; m_hi[i] = -1e30f;
    l_lo[i] = 0.f;    l_hi[i] = 0.f;
  }

  int pwBase = quad * 4 * 72 + l15;
  int prBase = l15 * 72 + quad * 8;
  int vrBase = l15 * 72 + quad * 8;

  int kvend_hi = hi * 64, kvend_lo = lo * 64;
  int buf = 0;
  for (int kv0 = 0; kv0 <= kvend_hi; kv0 += 64) {
    __syncthreads();
#pragma unroll
    for (int i = 0; i < 8; i++)
      vtw[(dgroup * 8 + i) * 36 + kp] = (u32)va[i] | ((u32)vb[i] << 16);
    __syncthreads();
    if (kv0 + 64 <= kvend_hi) {
      const u16* kS = kBase + (size_t)(kv0 + 64) * 3072;
#pragma unroll
      for (int i = 0; i < 2; i++) async_ld16(kS + kSrcOff[i], &Ks[buf ^ 1][kDstOff[i]]);
      const u16* vS = vBase + (size_t)(kv0 + 64 + 2 * kp) * 3072 + dgroup * 8;
      va = *reinterpret_cast<const u16x8*>(vS);
      vb = *reinterpret_cast<const u16x8*>(vS + 3072);
    }
    {
      const u16* KsB = &Ks[buf][0];
      ATTN_PROC(qf_hi, o_hi, m_hi, l_hi, q0_hi, kv0, KsB);
      if (kv0 <= kvend_lo)
        ATTN_PROC(qf_lo, o_lo, m_lo, l_lo, q0_lo, kv0, KsB);
    }
    buf ^= 1;
  }

#pragma unroll
  for (int r = 0; r < 4; r++) {
    float inv = 1.0f / l_hi[r];
    int row = b * Tn + q0_hi + quad * 4 + r;
#pragma unroll
    for (int dn = 0; dn < 4; dn++)
      y[(size_t)row * Cn + h * 64 + dn * 16 + l15] = f2b(o_hi[dn][r] * inv);
  }
#pragma unroll
  for (int r = 0; r < 4; r++) {
    float inv = 1.0f / l_lo[r];
    int row = b * Tn + q0_lo + quad * 4 + r;
#pragma unroll
    for (int dn = 0; dn < 4; dn++)
      y[(size_t)row * Cn + h * 64 + dn * 16 + l15] = f2b(o_lo[dn][r] * inv);
  }
}

// ---------------- launcher ----------------
extern "C" void kernel_launch(void* const* d_in, const int* in_sizes, int n_in,
                              void* d_out, int out_size, void* d_ws, size_t ws_size,
                              hipStream_t stream) {
  const void* x      = d_in[0];
  const void* ln1_w  = d_in[1];
  const void* ln1_b  = d_in[2];
  const void* w_qkv  = d_in[3];
  const void* b_qkv  = d_in[4];
  const void* w_o    = d_in[5];
  const void* b_o    = d_in[6];
  const void* ln2_w  = d_in[7];
  const void* ln2_b  = d_in[8];
  const void* w_fc   = d_in[9];
  const void* b_fc   = d_in[10];
  const void* w_proj = d_in[11];
  const void* b_proj = d_in[12];
  const u32* flagp = (const u32*)ln1_w;

  size_t off = 0;
  char* wsb = (char*)d_ws;
  auto alloc = [&](size_t bytes) {
    void* p = wsb + off;
    off += (bytes + 255) & ~(size_t)255;
    return (u16*)p;
  };
  u16* wqkvT  = alloc((size_t)3072 * 1024 * 2);
  u16* woT    = alloc((size_t)1024 * 1024 * 2);
  u16* wfcT   = alloc((size_t)4096 * 1024 * 2);
  u16* wprojT = alloc((size_t)1024 * 4096 * 2);
  u16* xb     = alloc((size_t)Mn * 1024 * 2);
  u16* sm     = alloc((size_t)16384 * 2);
  u16* xn     = alloc((size_t)Mn * 1024 * 2);
  u16* ybuf   = alloc((size_t)Mn * 1024 * 2);
  u16* x1     = alloc((size_t)Mn * 1024 * 2);
  u16* big    = alloc((size_t)Mn * 4096 * 2);
  u16* qkvbuf = big;
  u16* hbuf   = big;
  if (off > ws_size) return;

  u16* LW1 = sm;          // 1024
  u16* LB1 = sm + 1024;   // 1024
  u16* BQKV = sm + 2048;  // 3072
  u16* BO  = sm + 5120;   // 1024
  u16* LW2 = sm + 6144;   // 1024
  u16* LB2 = sm + 7168;   // 1024
  u16* BFC = sm + 8192;   // 4096
  u16* BPJ = sm + 12288;  // 1024

  SmallCvt sc;
  sc.src[0] = ln1_w;  sc.dst[0] = LW1;  sc.n[0] = 1024;
  sc.src[1] = ln1_b;  sc.dst[1] = LB1;  sc.n[1] = 1024;
  sc.src[2] = b_qkv;  sc.dst[2] = BQKV; sc.n[2] = 3072;
  sc.src[3] = b_o;    sc.dst[3] = BO;   sc.n[3] = 1024;
  sc.src[4] = ln2_w;  sc.dst[4] = LW2;  sc.n[4] = 1024;
  sc.src[5] = ln2_b;  sc.dst[5] = LB2;  sc.n[5] = 1024;
  sc.src[6] = b_fc;   sc.dst[6] = BFC;  sc.n[6] = 4096;
  sc.src[7] = b_proj; sc.dst[7] = BPJ;  sc.n[7] = 1024;

  hipLaunchKernelGGL(cvt_small_k, dim3(52), dim3(256), 0, stream, sc, flagp);

  dim3 tb(32, 8);
  hipLaunchKernelGGL(transpose_k, dim3(3072 / 32, 1024 / 32), tb, 0, stream, w_qkv, wqkvT, 1024, 3072, flagp);
  hipLaunchKernelGGL(transpose_k, dim3(1024 / 32, 1024 / 32), tb, 0, stream, w_o, woT, 1024, 1024, flagp);
  hipLaunchKernelGGL(transpose_k, dim3(4096 / 32, 1024 / 32), tb, 0, stream, w_fc, wfcT, 1024, 4096, flagp);
  hipLaunchKernelGGL(transpose_k, dim3(1024 / 32, 4096 / 32), tb, 0, stream, w_proj, wprojT, 4096, 1024, flagp);

  hipLaunchKernelGGL(cvtln_k, dim3(Mn), dim3(256), 0, stream, x, LW1, LB1, xb, xn, flagp);
  hipLaunchKernelGGL((gemm6_k<1, 0, 0, 0>), dim3(3072 / 128, Mn / 256), dim3(512), 0, stream,
                     xn, wqkvT, BQKV, (const u16*)nullptr, (void*)qkvbuf, Mn, 3072, 1024);
  hipLaunchKernelGGL(attn_k, dim3(Bn * Hn, 8), dim3(256), 0, stream, qkvbuf, ybuf);
  hipLaunchKernelGGL((gemm_k<0, 1, 0>), dim3(1024 / 128, Mn / 128), dim3(256), 0, stream,
                     ybuf, woT, BO, xb, (void*)x1, Mn, 1024, 1024);
  hipLaunchKernelGGL(ln_k, dim3(Mn), dim3(256), 0, stream, x1, LW2, LB2, xn);
  hipLaunchKernelGGL((gemm6_k<2, 1, 0, 0>), dim3(4096 / 256, Mn / 256), dim3(512), 0, stream,
                     xn, wfcT, BFC, (const u16*)nullptr, (void*)hbuf, Mn, 4096, 1024);
  hipLaunchKernelGGL((gemm6_k<1, 0, 1, 1>), dim3(1024 / 128, Mn / 256), dim3(512), 0, stream,
                     hbuf, wprojT, BPJ, x1, d_out, Mn, 1024, 4096);
}